// Round 5
// baseline (472.723 us; speedup 1.0000x reference)
//
#include <hip/hip_runtime.h>
#include <hip/hip_bf16.h>
#include <math.h>

typedef __hip_bfloat16 bf16;
typedef __attribute__((ext_vector_type(8))) short short8;
typedef __attribute__((ext_vector_type(4))) float floatx4;

constexpr int BB   = 2;
constexpr int SS   = 2048;
constexpr int DIMc = 1024;
constexpr int Hc   = 16;
constexpr int HDc  = 64;
constexpr int FFNc = 4096;
constexpr int TOK  = BB * SS;
constexpr float EPSc = 1e-5f;

// ---------------------------------------------------------------------------
// direct global->LDS 16B async copy (per-lane global addr, wave-uniform LDS
// base + lane*16)
// ---------------------------------------------------------------------------
typedef __attribute__((address_space(1))) void gvoid;
typedef __attribute__((address_space(3))) void lvoid;
__device__ __forceinline__ void lds16(const void* g, void* l) {
    __builtin_amdgcn_global_load_lds((gvoid*)g, (lvoid*)l, 16, 0, 0);
}

__device__ __forceinline__ float fexp2(float x) { return __builtin_amdgcn_exp2f(x); }

// ---------------------------------------------------------------------------
// LayerNorm: block per token, fp32 in, bf16 out
// ---------------------------------------------------------------------------
__global__ __launch_bounds__(256) void ln_kernel(const float* __restrict__ x,
                                                 const float* __restrict__ g,
                                                 const float* __restrict__ b,
                                                 bf16* __restrict__ out) {
    int t = blockIdx.x;
    int tid = threadIdx.x;
    const float4* xr = (const float4*)(x + (size_t)t * DIMc);
    float4 v = xr[tid];
    float s  = v.x + v.y + v.z + v.w;
    float sq = v.x*v.x + v.y*v.y + v.z*v.z + v.w*v.w;
    for (int off = 1; off < 64; off <<= 1) {
        s  += __shfl_xor(s,  off, 64);
        sq += __shfl_xor(sq, off, 64);
    }
    __shared__ float ss[4], ssq[4];
    int wave = tid >> 6;
    if ((tid & 63) == 0) { ss[wave] = s; ssq[wave] = sq; }
    __syncthreads();
    s  = ss[0] + ss[1] + ss[2] + ss[3];
    sq = ssq[0] + ssq[1] + ssq[2] + ssq[3];
    float mu  = s * (1.0f / DIMc);
    float var = sq * (1.0f / DIMc) - mu * mu;
    float inv = rsqrtf(var + EPSc);
    float4 gg = ((const float4*)g)[tid];
    float4 bb = ((const float4*)b)[tid];
    size_t base = (size_t)t * DIMc + tid * 4;
    out[base + 0] = __float2bfloat16((v.x - mu) * inv * gg.x + bb.x);
    out[base + 1] = __float2bfloat16((v.y - mu) * inv * gg.y + bb.y);
    out[base + 2] = __float2bfloat16((v.z - mu) * inv * gg.z + bb.z);
    out[base + 3] = __float2bfloat16((v.w - mu) * inv * gg.w + bb.w);
}

// ---------------------------------------------------------------------------
// fp32 [K,N] -> bf16 [N,K] transpose-convert, 32x32 LDS tile
// ---------------------------------------------------------------------------
__global__ __launch_bounds__(256) void transpose_bf16(const float* __restrict__ in,
                                                      bf16* __restrict__ out,
                                                      int K, int N) {
    __shared__ float t[32][33];
    int k0 = blockIdx.y * 32, n0 = blockIdx.x * 32;
    int x = threadIdx.x & 31;
    int y = threadIdx.x >> 5;   // 0..7
#pragma unroll
    for (int i = 0; i < 4; ++i) {
        int k = y + i * 8;
        t[k][x] = in[(size_t)(k0 + k) * N + n0 + x];
    }
    __syncthreads();
#pragma unroll
    for (int i = 0; i < 4; ++i) {
        int n = y + i * 8;
        out[(size_t)(n0 + n) * K + k0 + x] = __float2bfloat16(t[x][n]);
    }
}

// ---------------------------------------------------------------------------
// bf16 MFMA GEMM (m97 structure): C[M,N] = epi(A[M,K] @ Bt[N,K]^T + bias)
// ---------------------------------------------------------------------------
template <int ACT, bool ADD_RES, bool OUT_BF16>
__global__ __launch_bounds__(256) void gemm_bt(const bf16* __restrict__ A,
                                               const bf16* __restrict__ Bt,
                                               const float* __restrict__ bias,
                                               const float* __restrict__ res,
                                               void* __restrict__ Cout,
                                               int M, int N, int K) {
    constexpr int BM = 128, BN = 128, BK = 32;
    __shared__ bf16 As[BM * BK];
    __shared__ bf16 Bs[BN * BK];
    const int tid = threadIdx.x;
    const int wave = tid >> 6, lane = tid & 63;
    const int lane15 = lane & 15, lgrp = lane >> 4;
    const int wm = (wave >> 1) * 64, wn = (wave & 1) * 64;
    const int row0 = blockIdx.y * BM, col0 = blockIdx.x * BN;

    floatx4 acc[4][4] = {};

    const int sr = tid >> 2;
    const int sc = (tid & 3) * 8;
    const bf16* ga = A  + (size_t)(row0 + sr) * K + sc;
    const bf16* gb = Bt + (size_t)(col0 + sr) * K + sc;
    bf16* la = As + wave * 512;
    bf16* lb = Bs + wave * 512;

    for (int k0 = 0; k0 < K; k0 += BK) {
        __syncthreads();
        lds16(ga + k0,                  la);
        lds16(ga + k0 + (size_t)64 * K, la + 2048);
        lds16(gb + k0,                  lb);
        lds16(gb + k0 + (size_t)64 * K, lb + 2048);
        __syncthreads();
        short8 af[4], bfr[4];
#pragma unroll
        for (int i = 0; i < 4; ++i)
            af[i] = *(const short8*)(As + (wm + i * 16 + lane15) * BK + lgrp * 8);
#pragma unroll
        for (int j = 0; j < 4; ++j)
            bfr[j] = *(const short8*)(Bs + (wn + j * 16 + lane15) * BK + lgrp * 8);
#pragma unroll
        for (int i = 0; i < 4; ++i)
#pragma unroll
            for (int j = 0; j < 4; ++j)
                acc[i][j] = __builtin_amdgcn_mfma_f32_16x16x32_bf16(af[i], bfr[j], acc[i][j], 0, 0, 0);
    }

#pragma unroll
    for (int i = 0; i < 4; ++i) {
#pragma unroll
        for (int j = 0; j < 4; ++j) {
            int col = col0 + wn + j * 16 + lane15;
            float bv = bias[col];
#pragma unroll
            for (int r = 0; r < 4; ++r) {
                int row = row0 + wm + i * 16 + lgrp * 4 + r;
                float v = acc[i][j][r] + bv;
                if (ACT == 1) v = 0.5f * v * (1.0f + erff(v * 0.70710678118654752f));
                if (ADD_RES) v += res[(size_t)row * N + col];
                if (OUT_BF16) ((bf16*)Cout)[(size_t)row * N + col] = __float2bfloat16(v);
                else          ((float*)Cout)[(size_t)row * N + col] = v;
            }
        }
    }
}

// ---------------------------------------------------------------------------
// Split-K bf16 MFMA GEMM, fp32 atomicAdd epilogue into Cout (pre-seeded with
// the residual). bias added only by the blockIdx.z==0 chunk.
// ---------------------------------------------------------------------------
__global__ __launch_bounds__(256) void gemm_bt_atomic(const bf16* __restrict__ A,
                                                      const bf16* __restrict__ Bt,
                                                      const float* __restrict__ bias,
                                                      float* __restrict__ Cout,
                                                      int M, int N, int K, int KCH) {
    constexpr int BM = 128, BN = 128, BK = 32;
    __shared__ bf16 As[BM * BK];
    __shared__ bf16 Bs[BN * BK];
    const int tid = threadIdx.x;
    const int wave = tid >> 6, lane = tid & 63;
    const int lane15 = lane & 15, lgrp = lane >> 4;
    const int wm = (wave >> 1) * 64, wn = (wave & 1) * 64;
    const int row0 = blockIdx.y * BM, col0 = blockIdx.x * BN;
    const int kbase = blockIdx.z * KCH;

    floatx4 acc[4][4] = {};

    const int sr = tid >> 2;
    const int sc = (tid & 3) * 8;
    const bf16* ga = A  + (size_t)(row0 + sr) * K + sc;
    const bf16* gb = Bt + (size_t)(col0 + sr) * K + sc;
    bf16* la = As + wave * 512;
    bf16* lb = Bs + wave * 512;

    for (int k0 = kbase; k0 < kbase + KCH; k0 += BK) {
        __syncthreads();
        lds16(ga + k0,                  la);
        lds16(ga + k0 + (size_t)64 * K, la + 2048);
        lds16(gb + k0,                  lb);
        lds16(gb + k0 + (size_t)64 * K, lb + 2048);
        __syncthreads();
        short8 af[4], bfr[4];
#pragma unroll
        for (int i = 0; i < 4; ++i)
            af[i] = *(const short8*)(As + (wm + i * 16 + lane15) * BK + lgrp * 8);
#pragma unroll
        for (int j = 0; j < 4; ++j)
            bfr[j] = *(const short8*)(Bs + (wn + j * 16 + lane15) * BK + lgrp * 8);
#pragma unroll
        for (int i = 0; i < 4; ++i)
#pragma unroll
            for (int j = 0; j < 4; ++j)
                acc[i][j] = __builtin_amdgcn_mfma_f32_16x16x32_bf16(af[i], bfr[j], acc[i][j], 0, 0, 0);
    }

    const bool addb = (blockIdx.z == 0);
#pragma unroll
    for (int i = 0; i < 4; ++i) {
#pragma unroll
        for (int j = 0; j < 4; ++j) {
            int col = col0 + wn + j * 16 + lane15;
            float bv = addb ? bias[col] : 0.0f;
#pragma unroll
            for (int r = 0; r < 4; ++r) {
                int row = row0 + wm + i * 16 + lgrp * 4 + r;
                atomicAdd(&Cout[(size_t)row * N + col], acc[i][j][r] + bv);
            }
        }
    }
}

// ---------------------------------------------------------------------------
// RoPE in-place on bf16 qkv [TOK, 3*DIM]
// ---------------------------------------------------------------------------
__global__ __launch_bounds__(256) void rope_kernel(bf16* __restrict__ qkv) {
    int t = blockIdx.x;
    int pos = t % SS;
    int tid = threadIdx.x;
    const float ln_theta = 9.210340371976184f; // ln(10000)
    for (int idx = tid; idx < 1024; idx += 256) {
        int which = idx >> 9;
        int p = idx & 511;
        int head = p >> 5, d = p & 31;
        float inv_freq = __expf(-((float)(2 * d) / (float)HDc) * ln_theta);
        float ang = (float)pos * inv_freq;
        float sn, cs;
        __sincosf(ang, &sn, &cs);
        size_t base = (size_t)t * (3 * DIMc) + (size_t)which * DIMc + head * HDc + d;
        float x1 = __bfloat162float(qkv[base]);
        float x2 = __bfloat162float(qkv[base + 32]);
        qkv[base]      = __float2bfloat16(x1 * cs - x2 * sn);
        qkv[base + 32] = __float2bfloat16(x2 * cs + x1 * sn);
    }
}

// ---------------------------------------------------------------------------
// MFMA flash attention, no-max softmax. Block = 4 waves x 32 q-rows = 128.
// 36 MFMA per wave per 64-key tile (vs 18 at 16 q-rows/wave) to amortize the
// staging barriers. Grid (16,16,2) = 512 blocks.
// ---------------------------------------------------------------------------
__global__ __launch_bounds__(256) void attn_mfma(const bf16* __restrict__ qkv,
                                                 const unsigned char* __restrict__ mask,
                                                 bf16* __restrict__ ctx) {
    __shared__ short Klds[2][64][32];     // [kstep][key][32k]        8 KB
    __shared__ short Vt[64][72];          // [d][key] padded          9 KB
    __shared__ short Ps[4][32][72];       // per-wave P (Q-staging overlay) 18 KB
    __shared__ float mkf[64];

    const int b = blockIdx.z, h = blockIdx.y, q0 = blockIdx.x * 128;
    const int tid = threadIdx.x;
    const int wave = tid >> 6, lane = tid & 63;
    const int lane15 = lane & 15, lgrp = lane >> 4;
    const short* qs = (const short*)qkv;

    // stage this wave's Q tile (32 rows x 64) fragment-major [mi][s][row][32]
    // into the Ps overlay (4096 B of the wave's 4608 B slice)
    short* qstage = &Ps[wave][0][0];
#pragma unroll
    for (int i = 0; i < 4; ++i) {
        int idx = i * 64 + lane;   // unit of 8 shorts
        int g = idx & 3, row = (idx >> 2) & 15, s = (idx >> 6) & 1, mi = idx >> 7;
        const short* gq = qs + (size_t)(b * SS + q0 + wave * 32 + mi * 16 + row) * 3072
                             + h * 64 + s * 32 + g * 8;
        lds16(gq, qstage + idx * 8);
    }
    __syncthreads();
    short8 aQ[2][2];
#pragma unroll
    for (int mi = 0; mi < 2; ++mi)
#pragma unroll
        for (int s = 0; s < 2; ++s)
            aQ[mi][s] = *(const short8*)(qstage + ((mi * 2 + s) * 16 + lane15) * 32 + lgrp * 8);

    const short8 bOnes = (short8)(short)0x3F80;   // bf16 1.0 x8
    floatx4 O[2][4] = {};
    floatx4 Lacc[2] = {};
    const float cscale = 0.18033688011112042f; // 0.125 * log2(e)

    for (int k0 = 0; k0 < SS; k0 += 64) {
        __syncthreads();  // Klds/Vt WAR + Ps overlay WAR on first iter
        // K tile: fragment-major [s][key][32], per-lane gather, 16B to LDS
#pragma unroll
        for (int i = 0; i < 2; ++i) {
            int idx = wave * 128 + i * 64 + lane;
            int g = idx & 3, row = (idx >> 2) & 63, s = idx >> 8;
            const short* gk = qs + (size_t)(b * SS + k0 + row) * 3072 + 1024
                                 + h * 64 + s * 32 + g * 8;
            lds16(gk, &Klds[0][0][0] + idx * 8);
        }
        // V tile transposed: lane reads V[kk][dgrp*8..+7], writes Vt[d][kk]
#pragma unroll
        for (int c = 0; c < 2; ++c) {
            int idx = c * 256 + tid;
            int dgrp = idx >> 6, kk = idx & 63;
            const short8 vv = *(const short8*)(qs + (size_t)(b * SS + k0 + kk) * 3072
                                               + 2048 + h * 64 + dgrp * 8);
#pragma unroll
            for (int j = 0; j < 8; ++j) Vt[dgrp * 8 + j][kk] = vv[j];
        }
        if (tid < 16) {
            const unsigned char* mp = mask + b * SS + k0 + tid * 4;
#pragma unroll
            for (int j = 0; j < 4; ++j) mkf[tid * 4 + j] = mp[j] ? -1e30f : 0.0f;
        }
        __syncthreads();

        // QK^T: 16 MFMA
        short8 bK[4][2];
#pragma unroll
        for (int j = 0; j < 4; ++j)
#pragma unroll
            for (int s = 0; s < 2; ++s)
                bK[j][s] = *(const short8*)&Klds[s][j * 16 + lane15][lgrp * 8];
        floatx4 Sf[2][4] = {};
#pragma unroll
        for (int mi = 0; mi < 2; ++mi)
#pragma unroll
            for (int j = 0; j < 4; ++j)
#pragma unroll
                for (int s = 0; s < 2; ++s)
                    Sf[mi][j] = __builtin_amdgcn_mfma_f32_16x16x32_bf16(aQ[mi][s], bK[j][s], Sf[mi][j], 0, 0, 0);

        float mkv[4];
#pragma unroll
        for (int j = 0; j < 4; ++j) mkv[j] = mkf[j * 16 + lane15];

        // P = exp2(scale*S + mask); C-layout: col=lane15+16j, row=lgrp*4+r
#pragma unroll
        for (int mi = 0; mi < 2; ++mi)
#pragma unroll
            for (int r = 0; r < 4; ++r)
#pragma unroll
                for (int j = 0; j < 4; ++j) {
                    float p = fexp2(Sf[mi][j][r] * cscale + mkv[j]);
                    bf16 t = __float2bfloat16(p);
                    Ps[wave][mi * 16 + lgrp * 4 + r][lane15 + 16 * j] = *(short*)&t;
                }

        // PV (16 MFMA) + L (4 MFMA)
        short8 aP[2][2], bV[4][2];
#pragma unroll
        for (int mi = 0; mi < 2; ++mi)
#pragma unroll
            for (int s = 0; s < 2; ++s)
                aP[mi][s] = *(const short8*)&Ps[wave][mi * 16 + lane15][s * 32 + lgrp * 8];
#pragma unroll
        for (int jd = 0; jd < 4; ++jd)
#pragma unroll
            for (int s = 0; s < 2; ++s)
                bV[jd][s] = *(const short8*)&Vt[jd * 16 + lane15][s * 32 + lgrp * 8];
#pragma unroll
        for (int mi = 0; mi < 2; ++mi) {
#pragma unroll
            for (int jd = 0; jd < 4; ++jd)
#pragma unroll
                for (int s = 0; s < 2; ++s)
                    O[mi][jd] = __builtin_amdgcn_mfma_f32_16x16x32_bf16(aP[mi][s], bV[jd][s], O[mi][jd], 0, 0, 0);
#pragma unroll
            for (int s = 0; s < 2; ++s)
                Lacc[mi] = __builtin_amdgcn_mfma_f32_16x16x32_bf16(aP[mi][s], bOnes, Lacc[mi], 0, 0, 0);
        }
    }

    // epilogue: O /= L, write ctx [tok][dim]
#pragma unroll
    for (int mi = 0; mi < 2; ++mi)
#pragma unroll
        for (int r = 0; r < 4; ++r) {
            float inv = 1.0f / Lacc[mi][r];
            size_t rowoff = (size_t)(b * SS + q0 + wave * 32 + mi * 16 + lgrp * 4 + r) * DIMc
                            + h * 64 + lane15;
#pragma unroll
            for (int jd = 0; jd < 4; ++jd)
                ctx[rowoff + jd * 16] = __float2bfloat16(O[mi][jd][r] * inv);
        }
}

// ---------------------------------------------------------------------------
extern "C" void kernel_launch(void* const* d_in, const int* in_sizes, int n_in,
                              void* d_out, int out_size, void* d_ws, size_t ws_size,
                              hipStream_t stream) {
    const float* x      = (const float*)d_in[0];
    const unsigned char* pmask = (const unsigned char*)d_in[1];
    const float* qkv_w  = (const float*)d_in[2];
    const float* qkv_b  = (const float*)d_in[3];
    const float* out_w  = (const float*)d_in[4];
    const float* out_b  = (const float*)d_in[5];
    const float* ln1_g  = (const float*)d_in[6];
    const float* ln1_b  = (const float*)d_in[7];
    const float* ln2_g  = (const float*)d_in[8];
    const float* ln2_b  = (const float*)d_in[9];
    const float* w1     = (const float*)d_in[10];
    const float* b1     = (const float*)d_in[11];
    const float* w2     = (const float*)d_in[12];
    const float* b2     = (const float*)d_in[13];
    float* out = (float*)d_out;

    char* ws = (char*)d_ws;
    bf16* wqkv_t = (bf16*)ws;                      ws += (size_t)3072 * 1024 * 2;
    bf16* wout_t = (bf16*)ws;                      ws += (size_t)1024 * 1024 * 2;
    bf16* w1_t   = (bf16*)ws;                      ws += (size_t)4096 * 1024 * 2;
    bf16* w2_t   = (bf16*)ws;                      ws += (size_t)1024 * 4096 * 2;
    bf16* h_bf   = (bf16*)ws;                      ws += (size_t)TOK * DIMc * 2;
    bf16* qkv_bf = (bf16*)ws;                      ws += (size_t)TOK * 3 * DIMc * 2;
    bf16* ctx_bf = (bf16*)ws;                      ws += (size_t)TOK * DIMc * 2;
    bf16* ffn1_bf = qkv_bf;   // overlay

    transpose_bf16<<<dim3(3072 / 32, 1024 / 32), 256, 0, stream>>>(qkv_w, wqkv_t, 1024, 3072);
    transpose_bf16<<<dim3(1024 / 32, 1024 / 32), 256, 0, stream>>>(out_w, wout_t, 1024, 1024);
    transpose_bf16<<<dim3(4096 / 32, 1024 / 32), 256, 0, stream>>>(w1,    w1_t,   1024, 4096);
    transpose_bf16<<<dim3(1024 / 32, 4096 / 32), 256, 0, stream>>>(w2,    w2_t,   4096, 1024);

    ln_kernel<<<TOK, 256, 0, stream>>>(x, ln1_g, ln1_b, h_bf);
    gemm_bt<0, false, true><<<dim3(3072 / 128, TOK / 128), 256, 0, stream>>>(
        h_bf, wqkv_t, qkv_b, nullptr, qkv_bf, TOK, 3 * DIMc, DIMc);
    rope_kernel<<<TOK, 256, 0, stream>>>(qkv_bf);
    attn_mfma<<<dim3(SS / 128, Hc, BB), 256, 0, stream>>>(qkv_bf, pmask, ctx_bf);

    // seed d_out with residual x, then split-K atomic out-projection
    hipMemcpyAsync(out, x, (size_t)TOK * DIMc * sizeof(float),
                   hipMemcpyDeviceToDevice, stream);
    gemm_bt_atomic<<<dim3(1024 / 128, TOK / 128, 2), 256, 0, stream>>>(
        ctx_bf, wout_t, out_b, out, TOK, DIMc, DIMc, 512);

    ln_kernel<<<TOK, 256, 0, stream>>>(out, ln2_g, ln2_b, h_bf);
    gemm_bt<1, false, true><<<dim3(4096 / 128, TOK / 128), 256, 0, stream>>>(
        h_bf, w1_t, b1, nullptr, ffn1_bf, TOK, FFNc, DIMc);
    // FFN2: split-K=4 atomic accumulate into d_out (holds residual2)
    gemm_bt_atomic<<<dim3(1024 / 128, TOK / 128, 4), 256, 0, stream>>>(
        ffn1_bf, w2_t, b2, out, TOK, DIMc, FFNc, 1024);
}

// Round 6
// 430.245 us; speedup vs baseline: 1.0987x; 1.0987x over previous
//
#include <hip/hip_runtime.h>
#include <hip/hip_bf16.h>
#include <math.h>

typedef __hip_bfloat16 bf16;
typedef __attribute__((ext_vector_type(8))) short short8;
typedef __attribute__((ext_vector_type(4))) float floatx4;

constexpr int BB   = 2;
constexpr int SS   = 2048;
constexpr int DIMc = 1024;
constexpr int Hc   = 16;
constexpr int HDc  = 64;
constexpr int FFNc = 4096;
constexpr int TOK  = BB * SS;
constexpr float EPSc = 1e-5f;

// ---------------------------------------------------------------------------
// direct global->LDS 16B async copy (per-lane global addr, wave-uniform LDS
// base + lane*16)
// ---------------------------------------------------------------------------
typedef __attribute__((address_space(1))) void gvoid;
typedef __attribute__((address_space(3))) void lvoid;
__device__ __forceinline__ void lds16(const void* g, void* l) {
    __builtin_amdgcn_global_load_lds((gvoid*)g, (lvoid*)l, 16, 0, 0);
}

__device__ __forceinline__ float fexp2(float x) { return __builtin_amdgcn_exp2f(x); }

// ---------------------------------------------------------------------------
// LayerNorm: block per token, fp32 in, bf16 out
// ---------------------------------------------------------------------------
__global__ __launch_bounds__(256) void ln_kernel(const float* __restrict__ x,
                                                 const float* __restrict__ g,
                                                 const float* __restrict__ b,
                                                 bf16* __restrict__ out) {
    int t = blockIdx.x;
    int tid = threadIdx.x;
    const float4* xr = (const float4*)(x + (size_t)t * DIMc);
    float4 v = xr[tid];
    float s  = v.x + v.y + v.z + v.w;
    float sq = v.x*v.x + v.y*v.y + v.z*v.z + v.w*v.w;
    for (int off = 1; off < 64; off <<= 1) {
        s  += __shfl_xor(s,  off, 64);
        sq += __shfl_xor(sq, off, 64);
    }
    __shared__ float ss[4], ssq[4];
    int wave = tid >> 6;
    if ((tid & 63) == 0) { ss[wave] = s; ssq[wave] = sq; }
    __syncthreads();
    s  = ss[0] + ss[1] + ss[2] + ss[3];
    sq = ssq[0] + ssq[1] + ssq[2] + ssq[3];
    float mu  = s * (1.0f / DIMc);
    float var = sq * (1.0f / DIMc) - mu * mu;
    float inv = rsqrtf(var + EPSc);
    float4 gg = ((const float4*)g)[tid];
    float4 bb = ((const float4*)b)[tid];
    size_t base = (size_t)t * DIMc + tid * 4;
    out[base + 0] = __float2bfloat16((v.x - mu) * inv * gg.x + bb.x);
    out[base + 1] = __float2bfloat16((v.y - mu) * inv * gg.y + bb.y);
    out[base + 2] = __float2bfloat16((v.z - mu) * inv * gg.z + bb.z);
    out[base + 3] = __float2bfloat16((v.w - mu) * inv * gg.w + bb.w);
}

// ---------------------------------------------------------------------------
// Fused split-K reduce + bias + residual + LayerNorm (block per token):
// v = x + P0 + P1 + bias; out = v (fp32); hout = LN(v) (bf16)
// ---------------------------------------------------------------------------
__global__ __launch_bounds__(256) void reduce_ln_kernel(const float* __restrict__ P,
                                                        const float* __restrict__ x,
                                                        const float* __restrict__ bias,
                                                        const float* __restrict__ g,
                                                        const float* __restrict__ b,
                                                        float* __restrict__ out,
                                                        bf16* __restrict__ hout) {
    int t = blockIdx.x;
    int tid = threadIdx.x;
    size_t off = (size_t)t * DIMc / 4 + tid;
    float4 v  = ((const float4*)x)[off];
    float4 p0 = ((const float4*)P)[off];
    float4 p1 = ((const float4*)P)[off + (size_t)TOK * DIMc / 4];
    float4 bv = ((const float4*)bias)[tid];
    v.x += p0.x + p1.x + bv.x;
    v.y += p0.y + p1.y + bv.y;
    v.z += p0.z + p1.z + bv.z;
    v.w += p0.w + p1.w + bv.w;
    ((float4*)out)[off] = v;

    float s  = v.x + v.y + v.z + v.w;
    float sq = v.x*v.x + v.y*v.y + v.z*v.z + v.w*v.w;
    for (int o = 1; o < 64; o <<= 1) {
        s  += __shfl_xor(s,  o, 64);
        sq += __shfl_xor(sq, o, 64);
    }
    __shared__ float ss[4], ssq[4];
    int wave = tid >> 6;
    if ((tid & 63) == 0) { ss[wave] = s; ssq[wave] = sq; }
    __syncthreads();
    s  = ss[0] + ss[1] + ss[2] + ss[3];
    sq = ssq[0] + ssq[1] + ssq[2] + ssq[3];
    float mu  = s * (1.0f / DIMc);
    float var = sq * (1.0f / DIMc) - mu * mu;
    float inv = rsqrtf(var + EPSc);
    float4 gg = ((const float4*)g)[tid];
    float4 bb = ((const float4*)b)[tid];
    size_t base = (size_t)t * DIMc + tid * 4;
    hout[base + 0] = __float2bfloat16((v.x - mu) * inv * gg.x + bb.x);
    hout[base + 1] = __float2bfloat16((v.y - mu) * inv * gg.y + bb.y);
    hout[base + 2] = __float2bfloat16((v.z - mu) * inv * gg.z + bb.z);
    hout[base + 3] = __float2bfloat16((v.w - mu) * inv * gg.w + bb.w);
}

// ---------------------------------------------------------------------------
// Elementwise split-K reduce + bias into out (fp32, holds residual):
// out[i] += P0[i] + P1[i] + bias[col]
// ---------------------------------------------------------------------------
__global__ __launch_bounds__(256) void reduce_add_kernel(const float* __restrict__ P,
                                                         const float* __restrict__ bias,
                                                         float* __restrict__ out) {
    size_t f = (size_t)blockIdx.x * 256 + threadIdx.x;   // float4 index
    float4 v  = ((float4*)out)[f];
    float4 p0 = ((const float4*)P)[f];
    float4 p1 = ((const float4*)P)[f + (size_t)TOK * DIMc / 4];
    float4 bv = ((const float4*)bias)[f & (DIMc / 4 - 1)];
    v.x += p0.x + p1.x + bv.x;
    v.y += p0.y + p1.y + bv.y;
    v.z += p0.z + p1.z + bv.z;
    v.w += p0.w + p1.w + bv.w;
    ((float4*)out)[f] = v;
}

// ---------------------------------------------------------------------------
// fp32 [K,N] -> bf16 [N,K] transpose-convert, 32x32 LDS tile
// ---------------------------------------------------------------------------
__global__ __launch_bounds__(256) void transpose_bf16(const float* __restrict__ in,
                                                      bf16* __restrict__ out,
                                                      int K, int N) {
    __shared__ float t[32][33];
    int k0 = blockIdx.y * 32, n0 = blockIdx.x * 32;
    int x = threadIdx.x & 31;
    int y = threadIdx.x >> 5;   // 0..7
#pragma unroll
    for (int i = 0; i < 4; ++i) {
        int k = y + i * 8;
        t[k][x] = in[(size_t)(k0 + k) * N + n0 + x];
    }
    __syncthreads();
#pragma unroll
    for (int i = 0; i < 4; ++i) {
        int n = y + i * 8;
        out[(size_t)(n0 + n) * K + k0 + x] = __float2bfloat16(t[x][n]);
    }
}

// ---------------------------------------------------------------------------
// bf16 MFMA GEMM (m97 structure): C[M,N] = epi(A[M,K] @ Bt[N,K]^T + bias)
// ---------------------------------------------------------------------------
template <int ACT, bool ADD_RES, bool OUT_BF16>
__global__ __launch_bounds__(256) void gemm_bt(const bf16* __restrict__ A,
                                               const bf16* __restrict__ Bt,
                                               const float* __restrict__ bias,
                                               const float* __restrict__ res,
                                               void* __restrict__ Cout,
                                               int M, int N, int K) {
    constexpr int BM = 128, BN = 128, BK = 32;
    __shared__ bf16 As[BM * BK];
    __shared__ bf16 Bs[BN * BK];
    const int tid = threadIdx.x;
    const int wave = tid >> 6, lane = tid & 63;
    const int lane15 = lane & 15, lgrp = lane >> 4;
    const int wm = (wave >> 1) * 64, wn = (wave & 1) * 64;
    const int row0 = blockIdx.y * BM, col0 = blockIdx.x * BN;

    floatx4 acc[4][4] = {};

    const int sr = tid >> 2;
    const int sc = (tid & 3) * 8;
    const bf16* ga = A  + (size_t)(row0 + sr) * K + sc;
    const bf16* gb = Bt + (size_t)(col0 + sr) * K + sc;
    bf16* la = As + wave * 512;
    bf16* lb = Bs + wave * 512;

    for (int k0 = 0; k0 < K; k0 += BK) {
        __syncthreads();
        lds16(ga + k0,                  la);
        lds16(ga + k0 + (size_t)64 * K, la + 2048);
        lds16(gb + k0,                  lb);
        lds16(gb + k0 + (size_t)64 * K, lb + 2048);
        __syncthreads();
        short8 af[4], bfr[4];
#pragma unroll
        for (int i = 0; i < 4; ++i)
            af[i] = *(const short8*)(As + (wm + i * 16 + lane15) * BK + lgrp * 8);
#pragma unroll
        for (int j = 0; j < 4; ++j)
            bfr[j] = *(const short8*)(Bs + (wn + j * 16 + lane15) * BK + lgrp * 8);
#pragma unroll
        for (int i = 0; i < 4; ++i)
#pragma unroll
            for (int j = 0; j < 4; ++j)
                acc[i][j] = __builtin_amdgcn_mfma_f32_16x16x32_bf16(af[i], bfr[j], acc[i][j], 0, 0, 0);
    }

#pragma unroll
    for (int i = 0; i < 4; ++i) {
#pragma unroll
        for (int j = 0; j < 4; ++j) {
            int col = col0 + wn + j * 16 + lane15;
            float bv = bias[col];
#pragma unroll
            for (int r = 0; r < 4; ++r) {
                int row = row0 + wm + i * 16 + lgrp * 4 + r;
                float v = acc[i][j][r] + bv;
                if (ACT == 1) v = 0.5f * v * (1.0f + erff(v * 0.70710678118654752f));
                if (ADD_RES) v += res[(size_t)row * N + col];
                if (OUT_BF16) ((bf16*)Cout)[(size_t)row * N + col] = __float2bfloat16(v);
                else          ((float*)Cout)[(size_t)row * N + col] = v;
            }
        }
    }
}

// ---------------------------------------------------------------------------
// Split-K bf16 MFMA GEMM writing fp32 partials: P[z][M][N] (no bias/act).
// ---------------------------------------------------------------------------
__global__ __launch_bounds__(256) void gemm_bt_splitk(const bf16* __restrict__ A,
                                                      const bf16* __restrict__ Bt,
                                                      float* __restrict__ P,
                                                      int M, int N, int K, int KCH) {
    constexpr int BM = 128, BN = 128, BK = 32;
    __shared__ bf16 As[BM * BK];
    __shared__ bf16 Bs[BN * BK];
    const int tid = threadIdx.x;
    const int wave = tid >> 6, lane = tid & 63;
    const int lane15 = lane & 15, lgrp = lane >> 4;
    const int wm = (wave >> 1) * 64, wn = (wave & 1) * 64;
    const int row0 = blockIdx.y * BM, col0 = blockIdx.x * BN;
    const int kbase = blockIdx.z * KCH;
    float* Cp = P + (size_t)blockIdx.z * M * N;

    floatx4 acc[4][4] = {};

    const int sr = tid >> 2;
    const int sc = (tid & 3) * 8;
    const bf16* ga = A  + (size_t)(row0 + sr) * K + sc;
    const bf16* gb = Bt + (size_t)(col0 + sr) * K + sc;
    bf16* la = As + wave * 512;
    bf16* lb = Bs + wave * 512;

    for (int k0 = kbase; k0 < kbase + KCH; k0 += BK) {
        __syncthreads();
        lds16(ga + k0,                  la);
        lds16(ga + k0 + (size_t)64 * K, la + 2048);
        lds16(gb + k0,                  lb);
        lds16(gb + k0 + (size_t)64 * K, lb + 2048);
        __syncthreads();
        short8 af[4], bfr[4];
#pragma unroll
        for (int i = 0; i < 4; ++i)
            af[i] = *(const short8*)(As + (wm + i * 16 + lane15) * BK + lgrp * 8);
#pragma unroll
        for (int j = 0; j < 4; ++j)
            bfr[j] = *(const short8*)(Bs + (wn + j * 16 + lane15) * BK + lgrp * 8);
#pragma unroll
        for (int i = 0; i < 4; ++i)
#pragma unroll
            for (int j = 0; j < 4; ++j)
                acc[i][j] = __builtin_amdgcn_mfma_f32_16x16x32_bf16(af[i], bfr[j], acc[i][j], 0, 0, 0);
    }

#pragma unroll
    for (int i = 0; i < 4; ++i)
#pragma unroll
        for (int j = 0; j < 4; ++j) {
            int col = col0 + wn + j * 16 + lane15;
#pragma unroll
            for (int r = 0; r < 4; ++r) {
                int row = row0 + wm + i * 16 + lgrp * 4 + r;
                Cp[(size_t)row * N + col] = acc[i][j][r];
            }
        }
}

// ---------------------------------------------------------------------------
// RoPE in-place on bf16 qkv [TOK, 3*DIM]
// ---------------------------------------------------------------------------
__global__ __launch_bounds__(256) void rope_kernel(bf16* __restrict__ qkv) {
    int t = blockIdx.x;
    int pos = t % SS;
    int tid = threadIdx.x;
    const float ln_theta = 9.210340371976184f; // ln(10000)
    for (int idx = tid; idx < 1024; idx += 256) {
        int which = idx >> 9;
        int p = idx & 511;
        int head = p >> 5, d = p & 31;
        float inv_freq = __expf(-((float)(2 * d) / (float)HDc) * ln_theta);
        float ang = (float)pos * inv_freq;
        float sn, cs;
        __sincosf(ang, &sn, &cs);
        size_t base = (size_t)t * (3 * DIMc) + (size_t)which * DIMc + head * HDc + d;
        float x1 = __bfloat162float(qkv[base]);
        float x2 = __bfloat162float(qkv[base + 32]);
        qkv[base]      = __float2bfloat16(x1 * cs - x2 * sn);
        qkv[base + 32] = __float2bfloat16(x2 * cs + x1 * sn);
    }
}

// ---------------------------------------------------------------------------
// MFMA flash attention, no-max softmax. Block = 4 waves x 32 q-rows = 128.
// ---------------------------------------------------------------------------
__global__ __launch_bounds__(256) void attn_mfma(const bf16* __restrict__ qkv,
                                                 const unsigned char* __restrict__ mask,
                                                 bf16* __restrict__ ctx) {
    __shared__ short Klds[2][64][32];     // [kstep][key][32k]        8 KB
    __shared__ short Vt[64][72];          // [d][key] padded          9 KB
    __shared__ short Ps[4][32][72];       // per-wave P (Q-staging overlay) 18 KB
    __shared__ float mkf[64];

    const int b = blockIdx.z, h = blockIdx.y, q0 = blockIdx.x * 128;
    const int tid = threadIdx.x;
    const int wave = tid >> 6, lane = tid & 63;
    const int lane15 = lane & 15, lgrp = lane >> 4;
    const short* qs = (const short*)qkv;

    short* qstage = &Ps[wave][0][0];
#pragma unroll
    for (int i = 0; i < 4; ++i) {
        int idx = i * 64 + lane;   // unit of 8 shorts
        int g = idx & 3, row = (idx >> 2) & 15, s = (idx >> 6) & 1, mi = idx >> 7;
        const short* gq = qs + (size_t)(b * SS + q0 + wave * 32 + mi * 16 + row) * 3072
                             + h * 64 + s * 32 + g * 8;
        lds16(gq, qstage + idx * 8);
    }
    __syncthreads();
    short8 aQ[2][2];
#pragma unroll
    for (int mi = 0; mi < 2; ++mi)
#pragma unroll
        for (int s = 0; s < 2; ++s)
            aQ[mi][s] = *(const short8*)(qstage + ((mi * 2 + s) * 16 + lane15) * 32 + lgrp * 8);

    const short8 bOnes = (short8)(short)0x3F80;   // bf16 1.0 x8
    floatx4 O[2][4] = {};
    floatx4 Lacc[2] = {};
    const float cscale = 0.18033688011112042f; // 0.125 * log2(e)

    for (int k0 = 0; k0 < SS; k0 += 64) {
        __syncthreads();
#pragma unroll
        for (int i = 0; i < 2; ++i) {
            int idx = wave * 128 + i * 64 + lane;
            int g = idx & 3, row = (idx >> 2) & 63, s = idx >> 8;
            const short* gk = qs + (size_t)(b * SS + k0 + row) * 3072 + 1024
                                 + h * 64 + s * 32 + g * 8;
            lds16(gk, &Klds[0][0][0] + idx * 8);
        }
#pragma unroll
        for (int c = 0; c < 2; ++c) {
            int idx = c * 256 + tid;
            int dgrp = idx >> 6, kk = idx & 63;
            const short8 vv = *(const short8*)(qs + (size_t)(b * SS + k0 + kk) * 3072
                                               + 2048 + h * 64 + dgrp * 8);
#pragma unroll
            for (int j = 0; j < 8; ++j) Vt[dgrp * 8 + j][kk] = vv[j];
        }
        if (tid < 16) {
            const unsigned char* mp = mask + b * SS + k0 + tid * 4;
#pragma unroll
            for (int j = 0; j < 4; ++j) mkf[tid * 4 + j] = mp[j] ? -1e30f : 0.0f;
        }
        __syncthreads();

        short8 bK[4][2];
#pragma unroll
        for (int j = 0; j < 4; ++j)
#pragma unroll
            for (int s = 0; s < 2; ++s)
                bK[j][s] = *(const short8*)&Klds[s][j * 16 + lane15][lgrp * 8];
        floatx4 Sf[2][4] = {};
#pragma unroll
        for (int mi = 0; mi < 2; ++mi)
#pragma unroll
            for (int j = 0; j < 4; ++j)
#pragma unroll
                for (int s = 0; s < 2; ++s)
                    Sf[mi][j] = __builtin_amdgcn_mfma_f32_16x16x32_bf16(aQ[mi][s], bK[j][s], Sf[mi][j], 0, 0, 0);

        float mkv[4];
#pragma unroll
        for (int j = 0; j < 4; ++j) mkv[j] = mkf[j * 16 + lane15];

#pragma unroll
        for (int mi = 0; mi < 2; ++mi)
#pragma unroll
            for (int r = 0; r < 4; ++r)
#pragma unroll
                for (int j = 0; j < 4; ++j) {
                    float p = fexp2(Sf[mi][j][r] * cscale + mkv[j]);
                    bf16 t = __float2bfloat16(p);
                    Ps[wave][mi * 16 + lgrp * 4 + r][lane15 + 16 * j] = *(short*)&t;
                }

        short8 aP[2][2], bV[4][2];
#pragma unroll
        for (int mi = 0; mi < 2; ++mi)
#pragma unroll
            for (int s = 0; s < 2; ++s)
                aP[mi][s] = *(const short8*)&Ps[wave][mi * 16 + lane15][s * 32 + lgrp * 8];
#pragma unroll
        for (int jd = 0; jd < 4; ++jd)
#pragma unroll
            for (int s = 0; s < 2; ++s)
                bV[jd][s] = *(const short8*)&Vt[jd * 16 + lane15][s * 32 + lgrp * 8];
#pragma unroll
        for (int mi = 0; mi < 2; ++mi) {
#pragma unroll
            for (int jd = 0; jd < 4; ++jd)
#pragma unroll
                for (int s = 0; s < 2; ++s)
                    O[mi][jd] = __builtin_amdgcn_mfma_f32_16x16x32_bf16(aP[mi][s], bV[jd][s], O[mi][jd], 0, 0, 0);
#pragma unroll
            for (int s = 0; s < 2; ++s)
                Lacc[mi] = __builtin_amdgcn_mfma_f32_16x16x32_bf16(aP[mi][s], bOnes, Lacc[mi], 0, 0, 0);
        }
    }

#pragma unroll
    for (int mi = 0; mi < 2; ++mi)
#pragma unroll
        for (int r = 0; r < 4; ++r) {
            float inv = 1.0f / Lacc[mi][r];
            size_t rowoff = (size_t)(b * SS + q0 + wave * 32 + mi * 16 + lgrp * 4 + r) * DIMc
                            + h * 64 + lane15;
#pragma unroll
            for (int jd = 0; jd < 4; ++jd)
                ctx[rowoff + jd * 16] = __float2bfloat16(O[mi][jd][r] * inv);
        }
}

// ---------------------------------------------------------------------------
extern "C" void kernel_launch(void* const* d_in, const int* in_sizes, int n_in,
                              void* d_out, int out_size, void* d_ws, size_t ws_size,
                              hipStream_t stream) {
    const float* x      = (const float*)d_in[0];
    const unsigned char* pmask = (const unsigned char*)d_in[1];
    const float* qkv_w  = (const float*)d_in[2];
    const float* qkv_b  = (const float*)d_in[3];
    const float* out_w  = (const float*)d_in[4];
    const float* out_b  = (const float*)d_in[5];
    const float* ln1_g  = (const float*)d_in[6];
    const float* ln1_b  = (const float*)d_in[7];
    const float* ln2_g  = (const float*)d_in[8];
    const float* ln2_b  = (const float*)d_in[9];
    const float* w1     = (const float*)d_in[10];
    const float* b1     = (const float*)d_in[11];
    const float* w2     = (const float*)d_in[12];
    const float* b2     = (const float*)d_in[13];
    float* out = (float*)d_out;

    char* ws = (char*)d_ws;
    bf16* wqkv_t = (bf16*)ws;                      ws += (size_t)3072 * 1024 * 2;
    bf16* wout_t = (bf16*)ws;                      ws += (size_t)1024 * 1024 * 2;
    bf16* w1_t   = (bf16*)ws;                      ws += (size_t)4096 * 1024 * 2;
    bf16* w2_t   = (bf16*)ws;                      ws += (size_t)1024 * 4096 * 2;
    bf16* h_bf   = (bf16*)ws;                      ws += (size_t)TOK * DIMc * 2;
    bf16* qkv_bf = (bf16*)ws;                      ws += (size_t)TOK * 3 * DIMc * 2;
    bf16* ctx_bf = (bf16*)ws;                      ws += (size_t)TOK * DIMc * 2;
    float* partial = (float*)ws;                   ws += (size_t)2 * TOK * DIMc * 4; // 32 MB
    bf16* ffn1_bf = qkv_bf;   // overlay (32 MB over dead qkv+ctx)

    transpose_bf16<<<dim3(3072 / 32, 1024 / 32), 256, 0, stream>>>(qkv_w, wqkv_t, 1024, 3072);
    transpose_bf16<<<dim3(1024 / 32, 1024 / 32), 256, 0, stream>>>(out_w, wout_t, 1024, 1024);
    transpose_bf16<<<dim3(4096 / 32, 1024 / 32), 256, 0, stream>>>(w1,    w1_t,   1024, 4096);
    transpose_bf16<<<dim3(1024 / 32, 4096 / 32), 256, 0, stream>>>(w2,    w2_t,   4096, 1024);

    ln_kernel<<<TOK, 256, 0, stream>>>(x, ln1_g, ln1_b, h_bf);
    gemm_bt<0, false, true><<<dim3(3072 / 128, TOK / 128), 256, 0, stream>>>(
        h_bf, wqkv_t, qkv_b, nullptr, qkv_bf, TOK, 3 * DIMc, DIMc);
    rope_kernel<<<TOK, 256, 0, stream>>>(qkv_bf);
    attn_mfma<<<dim3(SS / 128, Hc, BB), 256, 0, stream>>>(qkv_bf, pmask, ctx_bf);

    // out-projection: split-K=2 -> fp32 partials, then fused reduce+residual+LN2
    gemm_bt_splitk<<<dim3(1024 / 128, TOK / 128, 2), 256, 0, stream>>>(
        ctx_bf, wout_t, partial, TOK, DIMc, DIMc, 512);
    reduce_ln_kernel<<<TOK, 256, 0, stream>>>(partial, x, out_b, ln2_g, ln2_b, out, h_bf);

    // FFN1 + GELU
    gemm_bt<1, false, true><<<dim3(4096 / 128, TOK / 128), 256, 0, stream>>>(
        h_bf, w1_t, b1, nullptr, ffn1_bf, TOK, FFNc, DIMc);
    // FFN2: split-K=2 -> partials, then elementwise reduce+bias into out
    gemm_bt_splitk<<<dim3(1024 / 128, TOK / 128, 2), 256, 0, stream>>>(
        ffn1_bf, w2_t, partial, TOK, DIMc, FFNc, 2048);
    reduce_add_kernel<<<TOK * DIMc / 4 / 256, 256, 0, stream>>>(partial, b2, out);
}

// Round 7
// 406.203 us; speedup vs baseline: 1.1638x; 1.0592x over previous
//
#include <hip/hip_runtime.h>
#include <hip/hip_bf16.h>
#include <math.h>

typedef __hip_bfloat16 bf16;
typedef __attribute__((ext_vector_type(8))) short short8;
typedef __attribute__((ext_vector_type(4))) float floatx4;

constexpr int BB   = 2;
constexpr int SS   = 2048;
constexpr int DIMc = 1024;
constexpr int Hc   = 16;
constexpr int HDc  = 64;
constexpr int FFNc = 4096;
constexpr int TOK  = BB * SS;
constexpr float EPSc = 1e-5f;

typedef __attribute__((address_space(1))) void gvoid;
typedef __attribute__((address_space(3))) void lvoid;
__device__ __forceinline__ void lds16(const void* g, void* l) {
    __builtin_amdgcn_global_load_lds((gvoid*)g, (lvoid*)l, 16, 0, 0);
}
__device__ __forceinline__ float fexp2(float x) { return __builtin_amdgcn_exp2f(x); }

// ---------------------------------------------------------------------------
// LayerNorm: block per token, fp32 in, bf16 out
// ---------------------------------------------------------------------------
__global__ __launch_bounds__(256) void ln_kernel(const float* __restrict__ x,
                                                 const float* __restrict__ g,
                                                 const float* __restrict__ b,
                                                 bf16* __restrict__ out) {
    int t = blockIdx.x;
    int tid = threadIdx.x;
    float4 v = ((const float4*)(x + (size_t)t * DIMc))[tid];
    float s  = v.x + v.y + v.z + v.w;
    float sq = v.x*v.x + v.y*v.y + v.z*v.z + v.w*v.w;
    for (int off = 1; off < 64; off <<= 1) {
        s  += __shfl_xor(s,  off, 64);
        sq += __shfl_xor(sq, off, 64);
    }
    __shared__ float ss[4], ssq[4];
    int wave = tid >> 6;
    if ((tid & 63) == 0) { ss[wave] = s; ssq[wave] = sq; }
    __syncthreads();
    s  = ss[0] + ss[1] + ss[2] + ss[3];
    sq = ssq[0] + ssq[1] + ssq[2] + ssq[3];
    float mu  = s * (1.0f / DIMc);
    float var = sq * (1.0f / DIMc) - mu * mu;
    float inv = rsqrtf(var + EPSc);
    float4 gg = ((const float4*)g)[tid];
    float4 bb = ((const float4*)b)[tid];
    size_t base = (size_t)t * DIMc + tid * 4;
    out[base + 0] = __float2bfloat16((v.x - mu) * inv * gg.x + bb.x);
    out[base + 1] = __float2bfloat16((v.y - mu) * inv * gg.y + bb.y);
    out[base + 2] = __float2bfloat16((v.z - mu) * inv * gg.z + bb.z);
    out[base + 3] = __float2bfloat16((v.w - mu) * inv * gg.w + bb.w);
}

// ---------------------------------------------------------------------------
// Fused split-K reduce + bias + residual + LayerNorm (block per token)
// ---------------------------------------------------------------------------
__global__ __launch_bounds__(256) void reduce_ln_kernel(const float* __restrict__ P,
                                                        const float* __restrict__ x,
                                                        const float* __restrict__ bias,
                                                        const float* __restrict__ g,
                                                        const float* __restrict__ b,
                                                        float* __restrict__ out,
                                                        bf16* __restrict__ hout) {
    int t = blockIdx.x;
    int tid = threadIdx.x;
    size_t off = (size_t)t * DIMc / 4 + tid;
    float4 v  = ((const float4*)x)[off];
    float4 p0 = ((const float4*)P)[off];
    float4 p1 = ((const float4*)P)[off + (size_t)TOK * DIMc / 4];
    float4 bv = ((const float4*)bias)[tid];
    v.x += p0.x + p1.x + bv.x;
    v.y += p0.y + p1.y + bv.y;
    v.z += p0.z + p1.z + bv.z;
    v.w += p0.w + p1.w + bv.w;
    ((float4*)out)[off] = v;

    float s  = v.x + v.y + v.z + v.w;
    float sq = v.x*v.x + v.y*v.y + v.z*v.z + v.w*v.w;
    for (int o = 1; o < 64; o <<= 1) {
        s  += __shfl_xor(s,  o, 64);
        sq += __shfl_xor(sq, o, 64);
    }
    __shared__ float ss[4], ssq[4];
    int wave = tid >> 6;
    if ((tid & 63) == 0) { ss[wave] = s; ssq[wave] = sq; }
    __syncthreads();
    s  = ss[0] + ss[1] + ss[2] + ss[3];
    sq = ssq[0] + ssq[1] + ssq[2] + ssq[3];
    float mu  = s * (1.0f / DIMc);
    float var = sq * (1.0f / DIMc) - mu * mu;
    float inv = rsqrtf(var + EPSc);
    float4 gg = ((const float4*)g)[tid];
    float4 bb = ((const float4*)b)[tid];
    size_t base = (size_t)t * DIMc + tid * 4;
    hout[base + 0] = __float2bfloat16((v.x - mu) * inv * gg.x + bb.x);
    hout[base + 1] = __float2bfloat16((v.y - mu) * inv * gg.y + bb.y);
    hout[base + 2] = __float2bfloat16((v.z - mu) * inv * gg.z + bb.z);
    hout[base + 3] = __float2bfloat16((v.w - mu) * inv * gg.w + bb.w);
}

// ---------------------------------------------------------------------------
// Elementwise split-K reduce + bias into out (fp32, holds residual)
// ---------------------------------------------------------------------------
__global__ __launch_bounds__(256) void reduce_add_kernel(const float* __restrict__ P,
                                                         const float* __restrict__ bias,
                                                         float* __restrict__ out) {
    size_t f = (size_t)blockIdx.x * 256 + threadIdx.x;   // float4 index
    float4 v  = ((float4*)out)[f];
    float4 p0 = ((const float4*)P)[f];
    float4 p1 = ((const float4*)P)[f + (size_t)TOK * DIMc / 4];
    float4 bv = ((const float4*)bias)[f & (DIMc / 4 - 1)];
    v.x += p0.x + p1.x + bv.x;
    v.y += p0.y + p1.y + bv.y;
    v.z += p0.z + p1.z + bv.z;
    v.w += p0.w + p1.w + bv.w;
    ((float4*)out)[f] = v;
}

// ---------------------------------------------------------------------------
// fp32 [K,N] -> bf16 [N,K] transpose-convert, 32x32 LDS tile
// ---------------------------------------------------------------------------
__global__ __launch_bounds__(256) void transpose_bf16(const float* __restrict__ in,
                                                      bf16* __restrict__ out,
                                                      int K, int N) {
    __shared__ float t[32][33];
    int k0 = blockIdx.y * 32, n0 = blockIdx.x * 32;
    int x = threadIdx.x & 31;
    int y = threadIdx.x >> 5;
#pragma unroll
    for (int i = 0; i < 4; ++i) {
        int k = y + i * 8;
        t[k][x] = in[(size_t)(k0 + k) * N + n0 + x];
    }
    __syncthreads();
#pragma unroll
    for (int i = 0; i < 4; ++i) {
        int n = y + i * 8;
        out[(size_t)(n0 + n) * K + k0 + x] = __float2bfloat16(t[x][n]);
    }
}

// ---------------------------------------------------------------------------
// V pre-transpose: qkv[b,s,2048+h*64+d] -> vT[((b*16+h)*64+d)*SS + s]  (bf16)
// 64(s) x 64(d) tiles, grid (SS/64, Hc, BB)
// ---------------------------------------------------------------------------
__global__ __launch_bounds__(256) void transpose_v(const bf16* __restrict__ qkv,
                                                   bf16* __restrict__ vT) {
    __shared__ short t[64][72];
    const int s0 = blockIdx.x * 64, h = blockIdx.y, b = blockIdx.z;
    const int tid = threadIdx.x;
    const short* qs = (const short*)qkv;
#pragma unroll
    for (int it = 0; it < 2; ++it) {
        int idx = it * 256 + tid;         // short8 id
        int r = idx >> 3, c = (idx & 7) * 8;
        *(short8*)&t[r][c] = *(const short8*)(qs + (size_t)(b * SS + s0 + r) * 3072
                                              + 2048 + h * 64 + c);
    }
    __syncthreads();
#pragma unroll
    for (int it = 0; it < 2; ++it) {
        int idx = it * 256 + tid;
        int d = idx >> 3, cs = (idx & 7) * 8;
        short8 v;
#pragma unroll
        for (int j = 0; j < 8; ++j) v[j] = t[cs + j][d];
        *(short8*)((short*)vT + ((size_t)(b * Hc + h) * 64 + d) * SS + s0 + cs) = v;
    }
}

// ---------------------------------------------------------------------------
// bf16 MFMA GEMM, BK=64 (two m97-style 32-wide k-halves per barrier pair).
// C[M,N] = epi(A[M,K] @ Bt[N,K]^T + bias), bf16 out.
// ACT=1: exact GELU. ROPE: apply rotary to q/k region (col < 2048).
// ---------------------------------------------------------------------------
template <int ACT, bool ROPE>
__global__ __launch_bounds__(256) void gemm_bt(const bf16* __restrict__ A,
                                               const bf16* __restrict__ Bt,
                                               const float* __restrict__ bias,
                                               bf16* __restrict__ Cout,
                                               int M, int N, int K) {
    constexpr int BK = 64;
    __shared__ bf16 As[2][128 * 32];   // [k-half][row*32+col]
    __shared__ bf16 Bs[2][128 * 32];
    const int tid = threadIdx.x;
    const int wave = tid >> 6, lane = tid & 63;
    const int lane15 = lane & 15, lgrp = lane >> 4;
    const int wm = (wave >> 1) * 64, wn = (wave & 1) * 64;
    const int row0 = blockIdx.y * 128, col0 = blockIdx.x * 128;

    floatx4 acc[4][4] = {};

    const int srow = wave * 16 + (lane >> 2);   // staging row within 64-row half
    const int scol = (lane & 3) * 8;
    const bf16* ga = A  + (size_t)(row0 + srow) * K + scol;
    const bf16* gb = Bt + (size_t)(col0 + srow) * K + scol;

    for (int k0 = 0; k0 < K; k0 += BK) {
        __syncthreads();
#pragma unroll
        for (int p = 0; p < 4; ++p) {
            const size_t go = (size_t)((p & 1) * 64) * K + k0 + (p >> 1) * 32;
            lds16(ga + go, &As[p >> 1][(p & 1) * 2048 + wave * 512]);
            lds16(gb + go, &Bs[p >> 1][(p & 1) * 2048 + wave * 512]);
        }
        __syncthreads();
#pragma unroll
        for (int s = 0; s < 2; ++s) {
            short8 af[4], bfr[4];
#pragma unroll
            for (int i = 0; i < 4; ++i)
                af[i] = *(const short8*)(&As[s][(wm + i * 16 + lane15) * 32 + lgrp * 8]);
#pragma unroll
            for (int j = 0; j < 4; ++j)
                bfr[j] = *(const short8*)(&Bs[s][(wn + j * 16 + lane15) * 32 + lgrp * 8]);
#pragma unroll
            for (int i = 0; i < 4; ++i)
#pragma unroll
                for (int j = 0; j < 4; ++j)
                    acc[i][j] = __builtin_amdgcn_mfma_f32_16x16x32_bf16(af[i], bfr[j], acc[i][j], 0, 0, 0);
        }
    }

    const bool doRope = ROPE && (col0 < 2048);
    float invf0 = 0.f, invf1 = 0.f;
    if (ROPE) {
        // inv_freq = theta^(-d/32) = exp2(-d*log2(10000)/32); d = lane15 (j=0), 16+lane15 (j=1)
        invf0 = fexp2(-0.4152410118609203f * (float)lane15);
        invf1 = fexp2(-0.4152410118609203f * (float)(16 + lane15));
    }
    float bv[4];
#pragma unroll
    for (int j = 0; j < 4; ++j) bv[j] = bias[col0 + wn + j * 16 + lane15];

#pragma unroll
    for (int i = 0; i < 4; ++i) {
#pragma unroll
        for (int r = 0; r < 4; ++r) {
            int row = row0 + wm + i * 16 + lgrp * 4 + r;
            float v[4];
#pragma unroll
            for (int j = 0; j < 4; ++j) v[j] = acc[i][j][r] + bv[j];
            if (doRope) {
                float pos = (float)(row & (SS - 1));
                float s0, c0, s1, c1;
                __sincosf(pos * invf0, &s0, &c0);
                __sincosf(pos * invf1, &s1, &c1);
                float t0 = v[0] * c0 - v[2] * s0;
                float t1 = v[1] * c1 - v[3] * s1;
                float t2 = v[2] * c0 + v[0] * s0;
                float t3 = v[3] * c1 + v[1] * s1;
                v[0] = t0; v[1] = t1; v[2] = t2; v[3] = t3;
            }
#pragma unroll
            for (int j = 0; j < 4; ++j) {
                float o = v[j];
                if (ACT == 1) o = 0.5f * o * (1.0f + erff(o * 0.70710678118654752f));
                Cout[(size_t)row * N + col0 + wn + j * 16 + lane15] = __float2bfloat16(o);
            }
        }
    }
}

// ---------------------------------------------------------------------------
// Split-K bf16 MFMA GEMM, BK=64, writes fp32 partials P[z][M][N]
// ---------------------------------------------------------------------------
__global__ __launch_bounds__(256) void gemm_bt_splitk(const bf16* __restrict__ A,
                                                      const bf16* __restrict__ Bt,
                                                      float* __restrict__ P,
                                                      int M, int N, int K, int KCH) {
    constexpr int BK = 64;
    __shared__ bf16 As[2][128 * 32];
    __shared__ bf16 Bs[2][128 * 32];
    const int tid = threadIdx.x;
    const int wave = tid >> 6, lane = tid & 63;
    const int lane15 = lane & 15, lgrp = lane >> 4;
    const int wm = (wave >> 1) * 64, wn = (wave & 1) * 64;
    const int row0 = blockIdx.y * 128, col0 = blockIdx.x * 128;
    const int kbase = blockIdx.z * KCH;
    float* Cp = P + (size_t)blockIdx.z * M * N;

    floatx4 acc[4][4] = {};

    const int srow = wave * 16 + (lane >> 2);
    const int scol = (lane & 3) * 8;
    const bf16* ga = A  + (size_t)(row0 + srow) * K + scol;
    const bf16* gb = Bt + (size_t)(col0 + srow) * K + scol;

    for (int k0 = kbase; k0 < kbase + KCH; k0 += BK) {
        __syncthreads();
#pragma unroll
        for (int p = 0; p < 4; ++p) {
            const size_t go = (size_t)((p & 1) * 64) * K + k0 + (p >> 1) * 32;
            lds16(ga + go, &As[p >> 1][(p & 1) * 2048 + wave * 512]);
            lds16(gb + go, &Bs[p >> 1][(p & 1) * 2048 + wave * 512]);
        }
        __syncthreads();
#pragma unroll
        for (int s = 0; s < 2; ++s) {
            short8 af[4], bfr[4];
#pragma unroll
            for (int i = 0; i < 4; ++i)
                af[i] = *(const short8*)(&As[s][(wm + i * 16 + lane15) * 32 + lgrp * 8]);
#pragma unroll
            for (int j = 0; j < 4; ++j)
                bfr[j] = *(const short8*)(&Bs[s][(wn + j * 16 + lane15) * 32 + lgrp * 8]);
#pragma unroll
            for (int i = 0; i < 4; ++i)
#pragma unroll
                for (int j = 0; j < 4; ++j)
                    acc[i][j] = __builtin_amdgcn_mfma_f32_16x16x32_bf16(af[i], bfr[j], acc[i][j], 0, 0, 0);
        }
    }

#pragma unroll
    for (int i = 0; i < 4; ++i)
#pragma unroll
        for (int j = 0; j < 4; ++j) {
            int col = col0 + wn + j * 16 + lane15;
#pragma unroll
            for (int r = 0; r < 4; ++r) {
                int row = row0 + wm + i * 16 + lgrp * 4 + r;
                Cp[(size_t)row * N + col] = acc[i][j][r];
            }
        }
}

// ---------------------------------------------------------------------------
// MFMA flash attention, no-max softmax, split-KV=2.
// Block = 4 waves x 32 q-rows = 128 q-rows; grid (16, Hc, BB*2) = 1024 blocks.
// Writes unnormalized O partials (fp32) + L partials; combine kernel finishes.
// ---------------------------------------------------------------------------
__global__ __launch_bounds__(256) void attn_mfma(const bf16* __restrict__ qkv,
                                                 const bf16* __restrict__ vT,
                                                 const unsigned char* __restrict__ mask,
                                                 float* __restrict__ Op,
                                                 float* __restrict__ Lp) {
    __shared__ short Klds[2][64][32];     // [kstep][key][32k]   8 KB
    __shared__ short Vlds[2][64][32];     // [kstep][d][32k]     8 KB
    __shared__ short Ps[4][32][72];       // per-wave P (Q-staging overlay) 18 KB
    __shared__ float mkf[64];

    const int h = blockIdx.y;
    const int b = blockIdx.z >> 1, kc = blockIdx.z & 1;
    const int q0 = blockIdx.x * 128;
    const int tid = threadIdx.x;
    const int wave = tid >> 6, lane = tid & 63;
    const int lane15 = lane & 15, lgrp = lane >> 4;
    const short* qs = (const short*)qkv;
    const short* vs = (const short*)vT + (size_t)(b * Hc + h) * 64 * SS;

    // stage this wave's Q tile (32 rows x 64) fragment-major into Ps overlay
    short* qstage = &Ps[wave][0][0];
#pragma unroll
    for (int i = 0; i < 4; ++i) {
        int idx = i * 64 + lane;   // unit of 8 shorts
        int g = idx & 3, row = (idx >> 2) & 15, s = (idx >> 6) & 1, mi = idx >> 7;
        const short* gq = qs + (size_t)(b * SS + q0 + wave * 32 + mi * 16 + row) * 3072
                             + h * 64 + s * 32 + g * 8;
        lds16(gq, qstage + idx * 8);
    }
    __syncthreads();
    short8 aQ[2][2];
#pragma unroll
    for (int mi = 0; mi < 2; ++mi)
#pragma unroll
        for (int s = 0; s < 2; ++s)
            aQ[mi][s] = *(const short8*)(qstage + ((mi * 2 + s) * 16 + lane15) * 32 + lgrp * 8);

    const short8 bOnes = (short8)(short)0x3F80;   // bf16 1.0 x8
    floatx4 O[2][4] = {};
    floatx4 Lacc[2] = {};
    const float cscale = 0.18033688011112042f; // 0.125 * log2(e)

    for (int t = 0; t < 16; ++t) {
        const int k0 = kc * 1024 + t * 64;
        __syncthreads();   // WAR on Klds/Vlds + Ps overlay (first iter)
        // K tile: fragment-major [s][key][32], per-lane gather, 16B to LDS
#pragma unroll
        for (int i = 0; i < 2; ++i) {
            int idx = wave * 128 + i * 64 + lane;
            int g = idx & 3, row = (idx >> 2) & 63, s = idx >> 8;
            const short* gk = qs + (size_t)(b * SS + k0 + row) * 3072 + 1024
                                 + h * 64 + s * 32 + g * 8;
            lds16(gk, &Klds[0][0][0] + idx * 8);
        }
        // V tile from pre-transposed vT: fragment-major [s][d][32]
#pragma unroll
        for (int i = 0; i < 2; ++i) {
            int idx = wave * 128 + i * 64 + lane;
            int g = idx & 3, drow = (idx >> 2) & 63, s = idx >> 8;
            const short* gv = vs + (size_t)drow * SS + k0 + s * 32 + g * 8;
            lds16(gv, &Vlds[0][0][0] + idx * 8);
        }
        if (tid < 16) {
            const unsigned char* mp = mask + b * SS + k0 + tid * 4;
#pragma unroll
            for (int j = 0; j < 4; ++j) mkf[tid * 4 + j] = mp[j] ? -1e30f : 0.0f;
        }
        __syncthreads();

        // QK^T: 16 MFMA
        short8 bK[4][2];
#pragma unroll
        for (int j = 0; j < 4; ++j)
#pragma unroll
            for (int s = 0; s < 2; ++s)
                bK[j][s] = *(const short8*)&Klds[s][j * 16 + lane15][lgrp * 8];
        floatx4 Sf[2][4] = {};
#pragma unroll
        for (int mi = 0; mi < 2; ++mi)
#pragma unroll
            for (int j = 0; j < 4; ++j)
#pragma unroll
                for (int s = 0; s < 2; ++s)
                    Sf[mi][j] = __builtin_amdgcn_mfma_f32_16x16x32_bf16(aQ[mi][s], bK[j][s], Sf[mi][j], 0, 0, 0);

        float mkv[4];
#pragma unroll
        for (int j = 0; j < 4; ++j) mkv[j] = mkf[j * 16 + lane15];

        // P = exp2(scale*S + mask); C-layout: col=lane15+16j, row=lgrp*4+r
#pragma unroll
        for (int mi = 0; mi < 2; ++mi)
#pragma unroll
            for (int r = 0; r < 4; ++r)
#pragma unroll
                for (int j = 0; j < 4; ++j) {
                    float p = fexp2(Sf[mi][j][r] * cscale + mkv[j]);
                    bf16 tt = __float2bfloat16(p);
                    Ps[wave][mi * 16 + lgrp * 4 + r][lane15 + 16 * j] = *(short*)&tt;
                }

        // PV (16 MFMA) + L (4 MFMA)
        short8 aP[2][2], bV[4][2];
#pragma unroll
        for (int mi = 0; mi < 2; ++mi)
#pragma unroll
            for (int s = 0; s < 2; ++s)
                aP[mi][s] = *(const short8*)&Ps[wave][mi * 16 + lane15][s * 32 + lgrp * 8];
#pragma unroll
        for (int jd = 0; jd < 4; ++jd)
#pragma unroll
            for (int s = 0; s < 2; ++s)
                bV[jd][s] = *(const short8*)&Vlds[s][jd * 16 + lane15][lgrp * 8];
#pragma unroll
        for (int mi = 0; mi < 2; ++mi) {
#pragma unroll
            for (int jd = 0; jd < 4; ++jd)
#pragma unroll
                for (int s = 0; s < 2; ++s)
                    O[mi][jd] = __builtin_amdgcn_mfma_f32_16x16x32_bf16(aP[mi][s], bV[jd][s], O[mi][jd], 0, 0, 0);
#pragma unroll
            for (int s = 0; s < 2; ++s)
                Lacc[mi] = __builtin_amdgcn_mfma_f32_16x16x32_bf16(aP[mi][s], bOnes, Lacc[mi], 0, 0, 0);
        }
    }

    // epilogue: unnormalized partials
    float* myOp = Op + (size_t)kc * TOK * DIMc;
#pragma unroll
    for (int mi = 0; mi < 2; ++mi)
#pragma unroll
        for (int r = 0; r < 4; ++r) {
            int q = q0 + wave * 32 + mi * 16 + lgrp * 4 + r;
            size_t rowoff = (size_t)(b * SS + q) * DIMc + h * 64 + lane15;
#pragma unroll
            for (int jd = 0; jd < 4; ++jd)
                myOp[rowoff + jd * 16] = O[mi][jd][r];
            if (lane15 == 0)
                Lp[((size_t)kc * TOK + b * SS + q) * Hc + h] = Lacc[mi][r];
        }
}

// ---------------------------------------------------------------------------
// Combine split-KV partials: ctx = (O0 + O1) / (L0 + L1), bf16 out
// ---------------------------------------------------------------------------
__global__ __launch_bounds__(256) void attn_combine(const float* __restrict__ Op,
                                                    const float* __restrict__ Lp,
                                                    bf16* __restrict__ ctx) {
    int t = blockIdx.x;
    int tid = threadIdx.x;
    int h = tid >> 4;
    size_t f = (size_t)t * (DIMc / 4) + tid;
    float4 p0 = ((const float4*)Op)[f];
    float4 p1 = ((const float4*)Op)[f + (size_t)TOK * DIMc / 4];
    float inv = 1.0f / (Lp[(size_t)t * Hc + h] + Lp[((size_t)TOK + t) * Hc + h]);
    size_t base = (size_t)t * DIMc + tid * 4;
    ctx[base + 0] = __float2bfloat16((p0.x + p1.x) * inv);
    ctx[base + 1] = __float2bfloat16((p0.y + p1.y) * inv);
    ctx[base + 2] = __float2bfloat16((p0.z + p1.z) * inv);
    ctx[base + 3] = __float2bfloat16((p0.w + p1.w) * inv);
}

// ---------------------------------------------------------------------------
extern "C" void kernel_launch(void* const* d_in, const int* in_sizes, int n_in,
                              void* d_out, int out_size, void* d_ws, size_t ws_size,
                              hipStream_t stream) {
    const float* x      = (const float*)d_in[0];
    const unsigned char* pmask = (const unsigned char*)d_in[1];
    const float* qkv_w  = (const float*)d_in[2];
    const float* qkv_b  = (const float*)d_in[3];
    const float* out_w  = (const float*)d_in[4];
    const float* out_b  = (const float*)d_in[5];
    const float* ln1_g  = (const float*)d_in[6];
    const float* ln1_b  = (const float*)d_in[7];
    const float* ln2_g  = (const float*)d_in[8];
    const float* ln2_b  = (const float*)d_in[9];
    const float* w1     = (const float*)d_in[10];
    const float* b1     = (const float*)d_in[11];
    const float* w2     = (const float*)d_in[12];
    const float* b2     = (const float*)d_in[13];
    float* out = (float*)d_out;

    char* ws = (char*)d_ws;
    bf16* wqkv_t = (bf16*)ws;                      ws += (size_t)3072 * 1024 * 2;
    bf16* wout_t = (bf16*)ws;                      ws += (size_t)1024 * 1024 * 2;
    bf16* w1_t   = (bf16*)ws;                      ws += (size_t)4096 * 1024 * 2;
    bf16* w2_t   = (bf16*)ws;                      ws += (size_t)1024 * 4096 * 2;
    bf16* h_bf   = (bf16*)ws;                      ws += (size_t)TOK * DIMc * 2;
    bf16* qkv_bf = (bf16*)ws;                      ws += (size_t)TOK * 3 * DIMc * 2;
    bf16* ctx_bf = (bf16*)ws;                      ws += (size_t)TOK * DIMc * 2;
    float* partial = (float*)ws;                   ws += (size_t)2 * TOK * DIMc * 4; // 32 MB
    float* Lp      = (float*)ws;                   ws += (size_t)2 * TOK * Hc * 4;   // 0.5 MB
    bf16* ffn1_bf = qkv_bf;          // overlay over dead qkv+ctx
    bf16* vT      = h_bf;            // overlay: h_bf dead between QKV gemm and reduce_ln

    transpose_bf16<<<dim3(3072 / 32, 1024 / 32), 256, 0, stream>>>(qkv_w, wqkv_t, 1024, 3072);
    transpose_bf16<<<dim3(1024 / 32, 1024 / 32), 256, 0, stream>>>(out_w, wout_t, 1024, 1024);
    transpose_bf16<<<dim3(4096 / 32, 1024 / 32), 256, 0, stream>>>(w1,    w1_t,   1024, 4096);
    transpose_bf16<<<dim3(1024 / 32, 4096 / 32), 256, 0, stream>>>(w2,    w2_t,   4096, 1024);

    ln_kernel<<<TOK, 256, 0, stream>>>(x, ln1_g, ln1_b, h_bf);
    // QKV + fused RoPE on q/k tiles
    gemm_bt<0, true><<<dim3(3072 / 128, TOK / 128), 256, 0, stream>>>(
        h_bf, wqkv_t, qkv_b, qkv_bf, TOK, 3 * DIMc, DIMc);
    // V pre-transpose (into dead h_bf region)
    transpose_v<<<dim3(SS / 64, Hc, BB), 256, 0, stream>>>(qkv_bf, vT);
    // attention: split-KV=2, partials + combine
    attn_mfma<<<dim3(SS / 128, Hc, BB * 2), 256, 0, stream>>>(qkv_bf, vT, pmask, partial, Lp);
    attn_combine<<<TOK, 256, 0, stream>>>(partial, Lp, ctx_bf);

    // out projection: split-K=2 -> fp32 partials, then fused reduce+residual+LN2
    gemm_bt_splitk<<<dim3(1024 / 128, TOK / 128, 2), 256, 0, stream>>>(
        ctx_bf, wout_t, partial, TOK, DIMc, DIMc, 512);
    reduce_ln_kernel<<<TOK, 256, 0, stream>>>(partial, x, out_b, ln2_g, ln2_b, out, h_bf);

    // FFN1 + GELU
    gemm_bt<1, false><<<dim3(4096 / 128, TOK / 128), 256, 0, stream>>>(
        h_bf, w1_t, b1, ffn1_bf, TOK, FFNc, DIMc);
    // FFN2: split-K=2 -> partials, then elementwise reduce+bias into out
    gemm_bt_splitk<<<dim3(1024 / 128, TOK / 128, 2), 256, 0, stream>>>(
        ffn1_bf, w2_t, partial, TOK, DIMc, FFNc, 2048);
    reduce_add_kernel<<<TOK * DIMc / 4 / 256, 256, 0, stream>>>(partial, b2, out);
}

// Round 8
// 391.455 us; speedup vs baseline: 1.2076x; 1.0377x over previous
//
#include <hip/hip_runtime.h>
#include <hip/hip_bf16.h>
#include <math.h>

typedef __hip_bfloat16 bf16;
typedef __attribute__((ext_vector_type(8))) short short8;
typedef __attribute__((ext_vector_type(4))) float floatx4;

constexpr int BB   = 2;
constexpr int SS   = 2048;
constexpr int DIMc = 1024;
constexpr int Hc   = 16;
constexpr int HDc  = 64;
constexpr int FFNc = 4096;
constexpr int TOK  = BB * SS;
constexpr float EPSc = 1e-5f;

typedef __attribute__((address_space(1))) void gvoid;
typedef __attribute__((address_space(3))) void lvoid;
__device__ __forceinline__ void lds16(const void* g, void* l) {
    __builtin_amdgcn_global_load_lds((gvoid*)g, (lvoid*)l, 16, 0, 0);
}
__device__ __forceinline__ float fexp2(float x) { return __builtin_amdgcn_exp2f(x); }

// ---------------------------------------------------------------------------
// LayerNorm: block per token, fp32 in, bf16 out
// ---------------------------------------------------------------------------
__global__ __launch_bounds__(256) void ln_kernel(const float* __restrict__ x,
                                                 const float* __restrict__ g,
                                                 const float* __restrict__ b,
                                                 bf16* __restrict__ out) {
    int t = blockIdx.x;
    int tid = threadIdx.x;
    float4 v = ((const float4*)(x + (size_t)t * DIMc))[tid];
    float s  = v.x + v.y + v.z + v.w;
    float sq = v.x*v.x + v.y*v.y + v.z*v.z + v.w*v.w;
    for (int off = 1; off < 64; off <<= 1) {
        s  += __shfl_xor(s,  off, 64);
        sq += __shfl_xor(sq, off, 64);
    }
    __shared__ float ss[4], ssq[4];
    int wave = tid >> 6;
    if ((tid & 63) == 0) { ss[wave] = s; ssq[wave] = sq; }
    __syncthreads();
    s  = ss[0] + ss[1] + ss[2] + ss[3];
    sq = ssq[0] + ssq[1] + ssq[2] + ssq[3];
    float mu  = s * (1.0f / DIMc);
    float var = sq * (1.0f / DIMc) - mu * mu;
    float inv = rsqrtf(var + EPSc);
    float4 gg = ((const float4*)g)[tid];
    float4 bb = ((const float4*)b)[tid];
    size_t base = (size_t)t * DIMc + tid * 4;
    out[base + 0] = __float2bfloat16((v.x - mu) * inv * gg.x + bb.x);
    out[base + 1] = __float2bfloat16((v.y - mu) * inv * gg.y + bb.y);
    out[base + 2] = __float2bfloat16((v.z - mu) * inv * gg.z + bb.z);
    out[base + 3] = __float2bfloat16((v.w - mu) * inv * gg.w + bb.w);
}

// ---------------------------------------------------------------------------
// Fused split-K reduce + bias + residual + LayerNorm (block per token)
// ---------------------------------------------------------------------------
__global__ __launch_bounds__(256) void reduce_ln_kernel(const float* __restrict__ P,
                                                        const float* __restrict__ x,
                                                        const float* __restrict__ bias,
                                                        const float* __restrict__ g,
                                                        const float* __restrict__ b,
                                                        float* __restrict__ out,
                                                        bf16* __restrict__ hout) {
    int t = blockIdx.x;
    int tid = threadIdx.x;
    size_t off = (size_t)t * DIMc / 4 + tid;
    float4 v  = ((const float4*)x)[off];
    float4 p0 = ((const float4*)P)[off];
    float4 p1 = ((const float4*)P)[off + (size_t)TOK * DIMc / 4];
    float4 bv = ((const float4*)bias)[tid];
    v.x += p0.x + p1.x + bv.x;
    v.y += p0.y + p1.y + bv.y;
    v.z += p0.z + p1.z + bv.z;
    v.w += p0.w + p1.w + bv.w;
    ((float4*)out)[off] = v;

    float s  = v.x + v.y + v.z + v.w;
    float sq = v.x*v.x + v.y*v.y + v.z*v.z + v.w*v.w;
    for (int o = 1; o < 64; o <<= 1) {
        s  += __shfl_xor(s,  o, 64);
        sq += __shfl_xor(sq, o, 64);
    }
    __shared__ float ss[4], ssq[4];
    int wave = tid >> 6;
    if ((tid & 63) == 0) { ss[wave] = s; ssq[wave] = sq; }
    __syncthreads();
    s  = ss[0] + ss[1] + ss[2] + ss[3];
    sq = ssq[0] + ssq[1] + ssq[2] + ssq[3];
    float mu  = s * (1.0f / DIMc);
    float var = sq * (1.0f / DIMc) - mu * mu;
    float inv = rsqrtf(var + EPSc);
    float4 gg = ((const float4*)g)[tid];
    float4 bb = ((const float4*)b)[tid];
    size_t base = (size_t)t * DIMc + tid * 4;
    hout[base + 0] = __float2bfloat16((v.x - mu) * inv * gg.x + bb.x);
    hout[base + 1] = __float2bfloat16((v.y - mu) * inv * gg.y + bb.y);
    hout[base + 2] = __float2bfloat16((v.z - mu) * inv * gg.z + bb.z);
    hout[base + 3] = __float2bfloat16((v.w - mu) * inv * gg.w + bb.w);
}

// ---------------------------------------------------------------------------
// Elementwise split-K reduce + bias into out (fp32, holds residual)
// ---------------------------------------------------------------------------
__global__ __launch_bounds__(256) void reduce_add_kernel(const float* __restrict__ P,
                                                         const float* __restrict__ bias,
                                                         float* __restrict__ out) {
    size_t f = (size_t)blockIdx.x * 256 + threadIdx.x;   // float4 index
    float4 v  = ((float4*)out)[f];
    float4 p0 = ((const float4*)P)[f];
    float4 p1 = ((const float4*)P)[f + (size_t)TOK * DIMc / 4];
    float4 bv = ((const float4*)bias)[f & (DIMc / 4 - 1)];
    v.x += p0.x + p1.x + bv.x;
    v.y += p0.y + p1.y + bv.y;
    v.z += p0.z + p1.z + bv.z;
    v.w += p0.w + p1.w + bv.w;
    ((float4*)out)[f] = v;
}

// ---------------------------------------------------------------------------
// fp32 [K,N] -> bf16 [N,K] transpose-convert, 32x32 LDS tile
// ---------------------------------------------------------------------------
__global__ __launch_bounds__(256) void transpose_bf16(const float* __restrict__ in,
                                                      bf16* __restrict__ out,
                                                      int K, int N) {
    __shared__ float t[32][33];
    int k0 = blockIdx.y * 32, n0 = blockIdx.x * 32;
    int x = threadIdx.x & 31;
    int y = threadIdx.x >> 5;
#pragma unroll
    for (int i = 0; i < 4; ++i) {
        int k = y + i * 8;
        t[k][x] = in[(size_t)(k0 + k) * N + n0 + x];
    }
    __syncthreads();
#pragma unroll
    for (int i = 0; i < 4; ++i) {
        int n = y + i * 8;
        out[(size_t)(n0 + n) * K + k0 + x] = __float2bfloat16(t[x][n]);
    }
}

// ---------------------------------------------------------------------------
// V pre-transpose: qkv[b,s,2048+h*64+d] -> vT[((b*16+h)*64+d)*SS + s]  (bf16)
// ---------------------------------------------------------------------------
__global__ __launch_bounds__(256) void transpose_v(const bf16* __restrict__ qkv,
                                                   bf16* __restrict__ vT) {
    __shared__ short t[64][72];
    const int s0 = blockIdx.x * 64, h = blockIdx.y, b = blockIdx.z;
    const int tid = threadIdx.x;
    const short* qs = (const short*)qkv;
#pragma unroll
    for (int it = 0; it < 2; ++it) {
        int idx = it * 256 + tid;         // short8 id
        int r = idx >> 3, c = (idx & 7) * 8;
        *(short8*)&t[r][c] = *(const short8*)(qs + (size_t)(b * SS + s0 + r) * 3072
                                              + 2048 + h * 64 + c);
    }
    __syncthreads();
#pragma unroll
    for (int it = 0; it < 2; ++it) {
        int idx = it * 256 + tid;
        int d = idx >> 3, cs = (idx & 7) * 8;
        short8 v;
#pragma unroll
        for (int j = 0; j < 8; ++j) v[j] = t[cs + j][d];
        *(short8*)((short*)vT + ((size_t)(b * Hc + h) * 64 + d) * SS + s0 + cs) = v;
    }
}

// ---------------------------------------------------------------------------
// XCD-aware block remap. Requires gridDim.y == 32 (all our GEMMs, M=4096).
// Blocks with lin%8 == k (same XCD under round-robin dispatch) tile a compact
// 8(m) x gn/2(n) region: 2MB of A stays resident in that XCD's private L2.
// ---------------------------------------------------------------------------
__device__ __forceinline__ void xcd_remap(int& bx, int& by) {
    const int gn = gridDim.x;
    int lin = blockIdx.y * gn + blockIdx.x;
    int k8 = lin & 7, idx = lin >> 3;
    int hn = gn >> 1;
    by = (k8 >> 1) * 8 + (idx & 7);
    bx = (k8 & 1) * hn + (idx >> 3);
}

// ---------------------------------------------------------------------------
// bf16 MFMA GEMM, BK=64, bank-conflict-swizzled LDS (slot g of row r holds
// k-chunk (g + (r>>1))&3 -> fragment ds_read_b128 is 2-way = free).
// ACT=1: exact GELU. ROPE: apply rotary to q/k region (col < 2048).
// ---------------------------------------------------------------------------
template <int ACT, bool ROPE>
__global__ __launch_bounds__(256) void gemm_bt(const bf16* __restrict__ A,
                                               const bf16* __restrict__ Bt,
                                               const float* __restrict__ bias,
                                               bf16* __restrict__ Cout,
                                               int M, int N, int K) {
    constexpr int BK = 64;
    __shared__ bf16 As[2][128 * 32];   // [k-half][row*32+col]
    __shared__ bf16 Bs[2][128 * 32];
    const int tid = threadIdx.x;
    const int wave = tid >> 6, lane = tid & 63;
    const int lane15 = lane & 15, lgrp = lane >> 4;
    const int wm = (wave >> 1) * 64, wn = (wave & 1) * 64;
    int bx, by; xcd_remap(bx, by);
    const int row0 = by * 128, col0 = bx * 128;

    floatx4 acc[4][4] = {};

    const int srow = wave * 16 + (lane >> 2);   // staging row within 64-row half
    const int scol = (((lane & 3) + (srow >> 1)) & 3) * 8;   // swizzled source chunk
    const bf16* ga = A  + (size_t)(row0 + srow) * K + scol;
    const bf16* gb = Bt + (size_t)(col0 + srow) * K + scol;
    const int g_l = (lgrp - (lane15 >> 1)) & 3;  // read slot for chunk lgrp

    for (int k0 = 0; k0 < K; k0 += BK) {
        __syncthreads();
#pragma unroll
        for (int p = 0; p < 4; ++p) {
            const size_t go = (size_t)((p & 1) * 64) * K + k0 + (p >> 1) * 32;
            lds16(ga + go, &As[p >> 1][(p & 1) * 2048 + wave * 512]);
            lds16(gb + go, &Bs[p >> 1][(p & 1) * 2048 + wave * 512]);
        }
        __syncthreads();
#pragma unroll
        for (int s = 0; s < 2; ++s) {
            short8 af[4], bfr[4];
#pragma unroll
            for (int i = 0; i < 4; ++i)
                af[i] = *(const short8*)(&As[s][(wm + i * 16 + lane15) * 32 + g_l * 8]);
#pragma unroll
            for (int j = 0; j < 4; ++j)
                bfr[j] = *(const short8*)(&Bs[s][(wn + j * 16 + lane15) * 32 + g_l * 8]);
#pragma unroll
            for (int i = 0; i < 4; ++i)
#pragma unroll
                for (int j = 0; j < 4; ++j)
                    acc[i][j] = __builtin_amdgcn_mfma_f32_16x16x32_bf16(af[i], bfr[j], acc[i][j], 0, 0, 0);
        }
    }

    const bool doRope = ROPE && (col0 < 2048);
    float invf0 = 0.f, invf1 = 0.f;
    if (ROPE) {
        invf0 = fexp2(-0.4152410118609203f * (float)lane15);
        invf1 = fexp2(-0.4152410118609203f * (float)(16 + lane15));
    }
    float bv[4];
#pragma unroll
    for (int j = 0; j < 4; ++j) bv[j] = bias[col0 + wn + j * 16 + lane15];

#pragma unroll
    for (int i = 0; i < 4; ++i) {
#pragma unroll
        for (int r = 0; r < 4; ++r) {
            int row = row0 + wm + i * 16 + lgrp * 4 + r;
            float v[4];
#pragma unroll
            for (int j = 0; j < 4; ++j) v[j] = acc[i][j][r] + bv[j];
            if (doRope) {
                float pos = (float)(row & (SS - 1));
                float s0, c0, s1, c1;
                __sincosf(pos * invf0, &s0, &c0);
                __sincosf(pos * invf1, &s1, &c1);
                float t0 = v[0] * c0 - v[2] * s0;
                float t1 = v[1] * c1 - v[3] * s1;
                float t2 = v[2] * c0 + v[0] * s0;
                float t3 = v[3] * c1 + v[1] * s1;
                v[0] = t0; v[1] = t1; v[2] = t2; v[3] = t3;
            }
#pragma unroll
            for (int j = 0; j < 4; ++j) {
                float o = v[j];
                if (ACT == 1) o = 0.5f * o * (1.0f + erff(o * 0.70710678118654752f));
                Cout[(size_t)row * N + col0 + wn + j * 16 + lane15] = __float2bfloat16(o);
            }
        }
    }
}

// ---------------------------------------------------------------------------
// Split-K bf16 MFMA GEMM, BK=64, swizzled LDS, writes fp32 partials P[z][M][N]
// ---------------------------------------------------------------------------
__global__ __launch_bounds__(256) void gemm_bt_splitk(const bf16* __restrict__ A,
                                                      const bf16* __restrict__ Bt,
                                                      float* __restrict__ P,
                                                      int M, int N, int K, int KCH) {
    constexpr int BK = 64;
    __shared__ bf16 As[2][128 * 32];
    __shared__ bf16 Bs[2][128 * 32];
    const int tid = threadIdx.x;
    const int wave = tid >> 6, lane = tid & 63;
    const int lane15 = lane & 15, lgrp = lane >> 4;
    const int wm = (wave >> 1) * 64, wn = (wave & 1) * 64;
    int bx, by; xcd_remap(bx, by);
    const int row0 = by * 128, col0 = bx * 128;
    const int kbase = blockIdx.z * KCH;
    float* Cp = P + (size_t)blockIdx.z * M * N;

    floatx4 acc[4][4] = {};

    const int srow = wave * 16 + (lane >> 2);
    const int scol = (((lane & 3) + (srow >> 1)) & 3) * 8;
    const bf16* ga = A  + (size_t)(row0 + srow) * K + scol;
    const bf16* gb = Bt + (size_t)(col0 + srow) * K + scol;
    const int g_l = (lgrp - (lane15 >> 1)) & 3;

    for (int k0 = kbase; k0 < kbase + KCH; k0 += BK) {
        __syncthreads();
#pragma unroll
        for (int p = 0; p < 4; ++p) {
            const size_t go = (size_t)((p & 1) * 64) * K + k0 + (p >> 1) * 32;
            lds16(ga + go, &As[p >> 1][(p & 1) * 2048 + wave * 512]);
            lds16(gb + go, &Bs[p >> 1][(p & 1) * 2048 + wave * 512]);
        }
        __syncthreads();
#pragma unroll
        for (int s = 0; s < 2; ++s) {
            short8 af[4], bfr[4];
#pragma unroll
            for (int i = 0; i < 4; ++i)
                af[i] = *(const short8*)(&As[s][(wm + i * 16 + lane15) * 32 + g_l * 8]);
#pragma unroll
            for (int j = 0; j < 4; ++j)
                bfr[j] = *(const short8*)(&Bs[s][(wn + j * 16 + lane15) * 32 + g_l * 8]);
#pragma unroll
            for (int i = 0; i < 4; ++i)
#pragma unroll
                for (int j = 0; j < 4; ++j)
                    acc[i][j] = __builtin_amdgcn_mfma_f32_16x16x32_bf16(af[i], bfr[j], acc[i][j], 0, 0, 0);
        }
    }

#pragma unroll
    for (int i = 0; i < 4; ++i)
#pragma unroll
        for (int j = 0; j < 4; ++j) {
            int col = col0 + wn + j * 16 + lane15;
#pragma unroll
            for (int r = 0; r < 4; ++r) {
                int row = row0 + wm + i * 16 + lgrp * 4 + r;
                Cp[(size_t)row * N + col] = acc[i][j][r];
            }
        }
}

// ---------------------------------------------------------------------------
// MFMA flash attention, no-max softmax, split-KV=2, swizzled K/V LDS.
// Block = 4 waves x 32 q-rows = 128 q-rows; grid (16, Hc, BB*2) = 1024 blocks.
// ---------------------------------------------------------------------------
__global__ __launch_bounds__(256) void attn_mfma(const bf16* __restrict__ qkv,
                                                 const bf16* __restrict__ vT,
                                                 const unsigned char* __restrict__ mask,
                                                 float* __restrict__ Op,
                                                 float* __restrict__ Lp) {
    __shared__ short Klds[2][64][32];     // [kstep][key][32k]   8 KB (swizzled)
    __shared__ short Vlds[2][64][32];     // [kstep][d][32k]     8 KB (swizzled)
    __shared__ short Ps[4][32][72];       // per-wave P (Q-staging overlay) 18 KB
    __shared__ float mkf[64];

    const int h = blockIdx.y;
    const int b = blockIdx.z >> 1, kc = blockIdx.z & 1;
    const int q0 = blockIdx.x * 128;
    const int tid = threadIdx.x;
    const int wave = tid >> 6, lane = tid & 63;
    const int lane15 = lane & 15, lgrp = lane >> 4;
    const short* qs = (const short*)qkv;
    const short* vs = (const short*)vT + (size_t)(b * Hc + h) * 64 * SS;
    const int g_l = (lgrp - (lane15 >> 1)) & 3;   // swizzled read slot

    // stage this wave's Q tile (32 rows x 64) fragment-major into Ps overlay
    short* qstage = &Ps[wave][0][0];
#pragma unroll
    for (int i = 0; i < 4; ++i) {
        int idx = i * 64 + lane;   // unit of 8 shorts
        int g = idx & 3, row = (idx >> 2) & 15, s = (idx >> 6) & 1, mi = idx >> 7;
        const short* gq = qs + (size_t)(b * SS + q0 + wave * 32 + mi * 16 + row) * 3072
                             + h * 64 + s * 32 + g * 8;
        lds16(gq, qstage + idx * 8);
    }
    __syncthreads();
    short8 aQ[2][2];
#pragma unroll
    for (int mi = 0; mi < 2; ++mi)
#pragma unroll
        for (int s = 0; s < 2; ++s)
            aQ[mi][s] = *(const short8*)(qstage + ((mi * 2 + s) * 16 + lane15) * 32 + lgrp * 8);

    const short8 bOnes = (short8)(short)0x3F80;   // bf16 1.0 x8
    floatx4 O[2][4] = {};
    floatx4 Lacc[2] = {};
    const float cscale = 0.18033688011112042f; // 0.125 * log2(e)

    for (int t = 0; t < 16; ++t) {
        const int k0 = kc * 1024 + t * 64;
        __syncthreads();   // WAR on Klds/Vlds + Ps overlay (first iter)
        // K tile: fragment-major [s][key][32], swizzled source chunk
#pragma unroll
        for (int i = 0; i < 2; ++i) {
            int idx = wave * 128 + i * 64 + lane;
            int g = idx & 3, row = (idx >> 2) & 63, s = idx >> 8;
            int gsw = (g + (row >> 1)) & 3;
            const short* gk = qs + (size_t)(b * SS + k0 + row) * 3072 + 1024
                                 + h * 64 + s * 32 + gsw * 8;
            lds16(gk, &Klds[0][0][0] + idx * 8);
        }
        // V tile from pre-transposed vT: fragment-major [s][d][32], swizzled
#pragma unroll
        for (int i = 0; i < 2; ++i) {
            int idx = wave * 128 + i * 64 + lane;
            int g = idx & 3, drow = (idx >> 2) & 63, s = idx >> 8;
            int gsw = (g + (drow >> 1)) & 3;
            const short* gv = vs + (size_t)drow * SS + k0 + s * 32 + gsw * 8;
            lds16(gv, &Vlds[0][0][0] + idx * 8);
        }
        if (tid < 16) {
            const unsigned char* mp = mask + b * SS + k0 + tid * 4;
#pragma unroll
            for (int j = 0; j < 4; ++j) mkf[tid * 4 + j] = mp[j] ? -1e30f : 0.0f;
        }
        __syncthreads();

        // QK^T: 16 MFMA
        short8 bK[4][2];
#pragma unroll
        for (int j = 0; j < 4; ++j)
#pragma unroll
            for (int s = 0; s < 2; ++s)
                bK[j][s] = *(const short8*)&Klds[s][j * 16 + lane15][g_l * 8];
        floatx4 Sf[2][4] = {};
#pragma unroll
        for (int mi = 0; mi < 2; ++mi)
#pragma unroll
            for (int j = 0; j < 4; ++j)
#pragma unroll
                for (int s = 0; s < 2; ++s)
                    Sf[mi][j] = __builtin_amdgcn_mfma_f32_16x16x32_bf16(aQ[mi][s], bK[j][s], Sf[mi][j], 0, 0, 0);

        float mkv[4];
#pragma unroll
        for (int j = 0; j < 4; ++j) mkv[j] = mkf[j * 16 + lane15];

        // P = exp2(scale*S + mask); C-layout: col=lane15+16j, row=lgrp*4+r
#pragma unroll
        for (int mi = 0; mi < 2; ++mi)
#pragma unroll
            for (int r = 0; r < 4; ++r)
#pragma unroll
                for (int j = 0; j < 4; ++j) {
                    float p = fexp2(Sf[mi][j][r] * cscale + mkv[j]);
                    bf16 tt = __float2bfloat16(p);
                    Ps[wave][mi * 16 + lgrp * 4 + r][lane15 + 16 * j] = *(short*)&tt;
                }

        // PV (16 MFMA) + L (4 MFMA)
        short8 aP[2][2], bV[4][2];
#pragma unroll
        for (int mi = 0; mi < 2; ++mi)
#pragma unroll
            for (int s = 0; s < 2; ++s)
                aP[mi][s] = *(const short8*)&Ps[wave][mi * 16 + lane15][s * 32 + lgrp * 8];
#pragma unroll
        for (int jd = 0; jd < 4; ++jd)
#pragma unroll
            for (int s = 0; s < 2; ++s)
                bV[jd][s] = *(const short8*)&Vlds[s][jd * 16 + lane15][g_l * 8];
#pragma unroll
        for (int mi = 0; mi < 2; ++mi) {
#pragma unroll
            for (int jd = 0; jd < 4; ++jd)
#pragma unroll
                for (int s = 0; s < 2; ++s)
                    O[mi][jd] = __builtin_amdgcn_mfma_f32_16x16x32_bf16(aP[mi][s], bV[jd][s], O[mi][jd], 0, 0, 0);
#pragma unroll
            for (int s = 0; s < 2; ++s)
                Lacc[mi] = __builtin_amdgcn_mfma_f32_16x16x32_bf16(aP[mi][s], bOnes, Lacc[mi], 0, 0, 0);
        }
    }

    // epilogue: unnormalized partials
    float* myOp = Op + (size_t)kc * TOK * DIMc;
#pragma unroll
    for (int mi = 0; mi < 2; ++mi)
#pragma unroll
        for (int r = 0; r < 4; ++r) {
            int q = q0 + wave * 32 + mi * 16 + lgrp * 4 + r;
            size_t rowoff = (size_t)(b * SS + q) * DIMc + h * 64 + lane15;
#pragma unroll
            for (int jd = 0; jd < 4; ++jd)
                myOp[rowoff + jd * 16] = O[mi][jd][r];
            if (lane15 == 0)
                Lp[((size_t)kc * TOK + b * SS + q) * Hc + h] = Lacc[mi][r];
        }
}

// ---------------------------------------------------------------------------
// Combine split-KV partials: ctx = (O0 + O1) / (L0 + L1), bf16 out
// ---------------------------------------------------------------------------
__global__ __launch_bounds__(256) void attn_combine(const float* __restrict__ Op,
                                                    const float* __restrict__ Lp,
                                                    bf16* __restrict__ ctx) {
    int t = blockIdx.x;
    int tid = threadIdx.x;
    int h = tid >> 4;
    size_t f = (size_t)t * (DIMc / 4) + tid;
    float4 p0 = ((const float4*)Op)[f];
    float4 p1 = ((const float4*)Op)[f + (size_t)TOK * DIMc / 4];
    float inv = 1.0f / (Lp[(size_t)t * Hc + h] + Lp[((size_t)TOK + t) * Hc + h]);
    size_t base = (size_t)t * DIMc + tid * 4;
    ctx[base + 0] = __float2bfloat16((p0.x + p1.x) * inv);
    ctx[base + 1] = __float2bfloat16((p0.y + p1.y) * inv);
    ctx[base + 2] = __float2bfloat16((p0.z + p1.z) * inv);
    ctx[base + 3] = __float2bfloat16((p0.w + p1.w) * inv);
}

// ---------------------------------------------------------------------------
extern "C" void kernel_launch(void* const* d_in, const int* in_sizes, int n_in,
                              void* d_out, int out_size, void* d_ws, size_t ws_size,
                              hipStream_t stream) {
    const float* x      = (const float*)d_in[0];
    const unsigned char* pmask = (const unsigned char*)d_in[1];
    const float* qkv_w  = (const float*)d_in[2];
    const float* qkv_b  = (const float*)d_in[3];
    const float* out_w  = (const float*)d_in[4];
    const float* out_b  = (const float*)d_in[5];
    const float* ln1_g  = (const float*)d_in[6];
    const float* ln1_b  = (const float*)d_in[7];
    const float* ln2_g  = (const float*)d_in[8];
    const float* ln2_b  = (const float*)d_in[9];
    const float* w1     = (const float*)d_in[10];
    const float* b1     = (const float*)d_in[11];
    const float* w2     = (const float*)d_in[12];
    const float* b2     = (const float*)d_in[13];
    float* out = (float*)d_out;

    char* ws = (char*)d_ws;
    bf16* wqkv_t = (bf16*)ws;                      ws += (size_t)3072 * 1024 * 2;
    bf16* wout_t = (bf16*)ws;                      ws += (size_t)1024 * 1024 * 2;
    bf16* w1_t   = (bf16*)ws;                      ws += (size_t)4096 * 1024 * 2;
    bf16* w2_t   = (bf16*)ws;                      ws += (size_t)1024 * 4096 * 2;
    bf16* h_bf   = (bf16*)ws;                      ws += (size_t)TOK * DIMc * 2;
    bf16* qkv_bf = (bf16*)ws;                      ws += (size_t)TOK * 3 * DIMc * 2;
    bf16* ctx_bf = (bf16*)ws;                      ws += (size_t)TOK * DIMc * 2;
    float* partial = (float*)ws;                   ws += (size_t)2 * TOK * DIMc * 4; // 32 MB
    float* Lp      = (float*)ws;                   ws += (size_t)2 * TOK * Hc * 4;   // 0.5 MB
    bf16* ffn1_bf = qkv_bf;          // overlay over dead qkv+ctx
    bf16* vT      = h_bf;            // overlay: h_bf dead between QKV gemm and reduce_ln

    transpose_bf16<<<dim3(3072 / 32, 1024 / 32), 256, 0, stream>>>(qkv_w, wqkv_t, 1024, 3072);
    transpose_bf16<<<dim3(1024 / 32, 1024 / 32), 256, 0, stream>>>(out_w, wout_t, 1024, 1024);
    transpose_bf16<<<dim3(4096 / 32, 1024 / 32), 256, 0, stream>>>(w1,    w1_t,   1024, 4096);
    transpose_bf16<<<dim3(1024 / 32, 4096 / 32), 256, 0, stream>>>(w2,    w2_t,   4096, 1024);

    ln_kernel<<<TOK, 256, 0, stream>>>(x, ln1_g, ln1_b, h_bf);
    // QKV + fused RoPE on q/k tiles
    gemm_bt<0, true><<<dim3(3072 / 128, TOK / 128), 256, 0, stream>>>(
        h_bf, wqkv_t, qkv_b, qkv_bf, TOK, 3 * DIMc, DIMc);
    // V pre-transpose (into dead h_bf region)
    transpose_v<<<dim3(SS / 64, Hc, BB), 256, 0, stream>>>(qkv_bf, vT);
    // attention: split-KV=2, partials + combine
    attn_mfma<<<dim3(SS / 128, Hc, BB * 2), 256, 0, stream>>>(qkv_bf, vT, pmask, partial, Lp);
    attn_combine<<<TOK, 256, 0, stream>>>(partial, Lp, ctx_bf);

    // out projection: split-K=2 -> fp32 partials, then fused reduce+residual+LN2
    gemm_bt_splitk<<<dim3(1024 / 128, TOK / 128, 2), 256, 0, stream>>>(
        ctx_bf, wout_t, partial, TOK, DIMc, DIMc, 512);
    reduce_ln_kernel<<<TOK, 256, 0, stream>>>(partial, x, out_b, ln2_g, ln2_b, out, h_bf);

    // FFN1 + GELU
    gemm_bt<1, false><<<dim3(4096 / 128, TOK / 128), 256, 0, stream>>>(
        h_bf, w1_t, b1, ffn1_bf, TOK, FFNc, DIMc);
    // FFN2: split-K=2 -> partials, then elementwise reduce+bias into out
    gemm_bt_splitk<<<dim3(1024 / 128, TOK / 128, 2), 256, 0, stream>>>(
        ffn1_bf, w2_t, partial, TOK, DIMc, FFNc, 2048);
    reduce_add_kernel<<<TOK * DIMc / 4 / 256, 256, 0, stream>>>(partial, b2, out);
}

// Round 9
// 371.133 us; speedup vs baseline: 1.2737x; 1.0548x over previous
//
#include <hip/hip_runtime.h>
#include <hip/hip_bf16.h>
#include <math.h>

typedef __hip_bfloat16 bf16;
typedef __attribute__((ext_vector_type(8))) short short8;
typedef __attribute__((ext_vector_type(4))) float floatx4;

constexpr int BB   = 2;
constexpr int SS   = 2048;
constexpr int DIMc = 1024;
constexpr int Hc   = 16;
constexpr int HDc  = 64;
constexpr int FFNc = 4096;
constexpr int TOK  = BB * SS;
constexpr float EPSc = 1e-5f;

typedef __attribute__((address_space(1))) void gvoid;
typedef __attribute__((address_space(3))) void lvoid;
__device__ __forceinline__ void lds16(const void* g, void* l) {
    __builtin_amdgcn_global_load_lds((gvoid*)g, (lvoid*)l, 16, 0, 0);
}
__device__ __forceinline__ float fexp2(float x) { return __builtin_amdgcn_exp2f(x); }

// tanh-form GELU via sigmoid: 0.5x(1+tanh(c(x+0.044715x^3))) = x*sigma(2c*(...))
// ~8 VALU + exp2 + rcp, vs ~35 inst for software erff. Max abs dev ~3e-4.
__device__ __forceinline__ float fast_gelu(float x) {
    float x2 = x * x;
    float z = 0.7978845608028654f * x * __builtin_fmaf(0.044715f, x2, 1.0f);
    float e = fexp2(-2.885390081777927f * z);          // exp(-2z)
    return x * __builtin_amdgcn_rcpf(1.0f + e);
}

// ---------------------------------------------------------------------------
// LayerNorm: block per token, fp32 in, bf16 out
// ---------------------------------------------------------------------------
__global__ __launch_bounds__(256) void ln_kernel(const float* __restrict__ x,
                                                 const float* __restrict__ g,
                                                 const float* __restrict__ b,
                                                 bf16* __restrict__ out) {
    int t = blockIdx.x;
    int tid = threadIdx.x;
    float4 v = ((const float4*)(x + (size_t)t * DIMc))[tid];
    float s  = v.x + v.y + v.z + v.w;
    float sq = v.x*v.x + v.y*v.y + v.z*v.z + v.w*v.w;
    for (int off = 1; off < 64; off <<= 1) {
        s  += __shfl_xor(s,  off, 64);
        sq += __shfl_xor(sq, off, 64);
    }
    __shared__ float ss[4], ssq[4];
    int wave = tid >> 6;
    if ((tid & 63) == 0) { ss[wave] = s; ssq[wave] = sq; }
    __syncthreads();
    s  = ss[0] + ss[1] + ss[2] + ss[3];
    sq = ssq[0] + ssq[1] + ssq[2] + ssq[3];
    float mu  = s * (1.0f / DIMc);
    float var = sq * (1.0f / DIMc) - mu * mu;
    float inv = rsqrtf(var + EPSc);
    float4 gg = ((const float4*)g)[tid];
    float4 bb = ((const float4*)b)[tid];
    size_t base = (size_t)t * DIMc + tid * 4;
    out[base + 0] = __float2bfloat16((v.x - mu) * inv * gg.x + bb.x);
    out[base + 1] = __float2bfloat16((v.y - mu) * inv * gg.y + bb.y);
    out[base + 2] = __float2bfloat16((v.z - mu) * inv * gg.z + bb.z);
    out[base + 3] = __float2bfloat16((v.w - mu) * inv * gg.w + bb.w);
}

// ---------------------------------------------------------------------------
// Fused split-K reduce + bias + residual + LayerNorm (block per token)
// ---------------------------------------------------------------------------
__global__ __launch_bounds__(256) void reduce_ln_kernel(const float* __restrict__ P,
                                                        const float* __restrict__ x,
                                                        const float* __restrict__ bias,
                                                        const float* __restrict__ g,
                                                        const float* __restrict__ b,
                                                        float* __restrict__ out,
                                                        bf16* __restrict__ hout) {
    int t = blockIdx.x;
    int tid = threadIdx.x;
    size_t off = (size_t)t * DIMc / 4 + tid;
    float4 v  = ((const float4*)x)[off];
    float4 p0 = ((const float4*)P)[off];
    float4 p1 = ((const float4*)P)[off + (size_t)TOK * DIMc / 4];
    float4 bv = ((const float4*)bias)[tid];
    v.x += p0.x + p1.x + bv.x;
    v.y += p0.y + p1.y + bv.y;
    v.z += p0.z + p1.z + bv.z;
    v.w += p0.w + p1.w + bv.w;
    ((float4*)out)[off] = v;

    float s  = v.x + v.y + v.z + v.w;
    float sq = v.x*v.x + v.y*v.y + v.z*v.z + v.w*v.w;
    for (int o = 1; o < 64; o <<= 1) {
        s  += __shfl_xor(s,  o, 64);
        sq += __shfl_xor(sq, o, 64);
    }
    __shared__ float ss[4], ssq[4];
    int wave = tid >> 6;
    if ((tid & 63) == 0) { ss[wave] = s; ssq[wave] = sq; }
    __syncthreads();
    s  = ss[0] + ss[1] + ss[2] + ss[3];
    sq = ssq[0] + ssq[1] + ssq[2] + ssq[3];
    float mu  = s * (1.0f / DIMc);
    float var = sq * (1.0f / DIMc) - mu * mu;
    float inv = rsqrtf(var + EPSc);
    float4 gg = ((const float4*)g)[tid];
    float4 bb = ((const float4*)b)[tid];
    size_t base = (size_t)t * DIMc + tid * 4;
    hout[base + 0] = __float2bfloat16((v.x - mu) * inv * gg.x + bb.x);
    hout[base + 1] = __float2bfloat16((v.y - mu) * inv * gg.y + bb.y);
    hout[base + 2] = __float2bfloat16((v.z - mu) * inv * gg.z + bb.z);
    hout[base + 3] = __float2bfloat16((v.w - mu) * inv * gg.w + bb.w);
}

// ---------------------------------------------------------------------------
// Elementwise split-K reduce + bias into out (fp32, holds residual)
// ---------------------------------------------------------------------------
__global__ __launch_bounds__(256) void reduce_add_kernel(const float* __restrict__ P,
                                                         const float* __restrict__ bias,
                                                         float* __restrict__ out) {
    size_t f = (size_t)blockIdx.x * 256 + threadIdx.x;   // float4 index
    float4 v  = ((float4*)out)[f];
    float4 p0 = ((const float4*)P)[f];
    float4 p1 = ((const float4*)P)[f + (size_t)TOK * DIMc / 4];
    float4 bv = ((const float4*)bias)[f & (DIMc / 4 - 1)];
    v.x += p0.x + p1.x + bv.x;
    v.y += p0.y + p1.y + bv.y;
    v.z += p0.z + p1.z + bv.z;
    v.w += p0.w + p1.w + bv.w;
    ((float4*)out)[f] = v;
}

// ---------------------------------------------------------------------------
// fp32 [K,N] -> bf16 [N,K] transpose-convert, 32x32 LDS tile
// ---------------------------------------------------------------------------
__global__ __launch_bounds__(256) void transpose_bf16(const float* __restrict__ in,
                                                      bf16* __restrict__ out,
                                                      int K, int N) {
    __shared__ float t[32][33];
    int k0 = blockIdx.y * 32, n0 = blockIdx.x * 32;
    int x = threadIdx.x & 31;
    int y = threadIdx.x >> 5;
#pragma unroll
    for (int i = 0; i < 4; ++i) {
        int k = y + i * 8;
        t[k][x] = in[(size_t)(k0 + k) * N + n0 + x];
    }
    __syncthreads();
#pragma unroll
    for (int i = 0; i < 4; ++i) {
        int n = y + i * 8;
        out[(size_t)(n0 + n) * K + k0 + x] = __float2bfloat16(t[x][n]);
    }
}

// ---------------------------------------------------------------------------
// V pre-transpose: qkv[b,s,2048+h*64+d] -> vT[((b*16+h)*64+d)*SS + s]  (bf16)
// ---------------------------------------------------------------------------
__global__ __launch_bounds__(256) void transpose_v(const bf16* __restrict__ qkv,
                                                   bf16* __restrict__ vT) {
    __shared__ short t[64][72];
    const int s0 = blockIdx.x * 64, h = blockIdx.y, b = blockIdx.z;
    const int tid = threadIdx.x;
    const short* qs = (const short*)qkv;
#pragma unroll
    for (int it = 0; it < 2; ++it) {
        int idx = it * 256 + tid;         // short8 id
        int r = idx >> 3, c = (idx & 7) * 8;
        *(short8*)&t[r][c] = *(const short8*)(qs + (size_t)(b * SS + s0 + r) * 3072
                                              + 2048 + h * 64 + c);
    }
    __syncthreads();
#pragma unroll
    for (int it = 0; it < 2; ++it) {
        int idx = it * 256 + tid;
        int d = idx >> 3, cs = (idx & 7) * 8;
        short8 v;
#pragma unroll
        for (int j = 0; j < 8; ++j) v[j] = t[cs + j][d];
        *(short8*)((short*)vT + ((size_t)(b * Hc + h) * 64 + d) * SS + s0 + cs) = v;
    }
}

// ---------------------------------------------------------------------------
// XCD-aware block remap. Requires gridDim.y == 32 (all our GEMMs, M=4096).
// ---------------------------------------------------------------------------
__device__ __forceinline__ void xcd_remap(int& bx, int& by) {
    const int gn = gridDim.x;
    int lin = blockIdx.y * gn + blockIdx.x;
    int k8 = lin & 7, idx = lin >> 3;
    int hn = gn >> 1;
    by = (k8 >> 1) * 8 + (idx & 7);
    bx = (k8 & 1) * hn + (idx >> 3);
}

// ---------------------------------------------------------------------------
// bf16 MFMA GEMM, BK=64, bank-conflict-swizzled LDS.
// ACT=1: fast GELU. ROPE: apply rotary to q/k region (col < 2048).
// ---------------------------------------------------------------------------
template <int ACT, bool ROPE>
__global__ __launch_bounds__(256) void gemm_bt(const bf16* __restrict__ A,
                                               const bf16* __restrict__ Bt,
                                               const float* __restrict__ bias,
                                               bf16* __restrict__ Cout,
                                               int M, int N, int K) {
    constexpr int BK = 64;
    __shared__ bf16 As[2][128 * 32];   // [k-half][row*32+col]
    __shared__ bf16 Bs[2][128 * 32];
    const int tid = threadIdx.x;
    const int wave = tid >> 6, lane = tid & 63;
    const int lane15 = lane & 15, lgrp = lane >> 4;
    const int wm = (wave >> 1) * 64, wn = (wave & 1) * 64;
    int bx, by; xcd_remap(bx, by);
    const int row0 = by * 128, col0 = bx * 128;

    floatx4 acc[4][4] = {};

    const int srow = wave * 16 + (lane >> 2);   // staging row within 64-row half
    const int scol = (((lane & 3) + (srow >> 1)) & 3) * 8;   // swizzled source chunk
    const bf16* ga = A  + (size_t)(row0 + srow) * K + scol;
    const bf16* gb = Bt + (size_t)(col0 + srow) * K + scol;
    const int g_l = (lgrp - (lane15 >> 1)) & 3;  // read slot for chunk lgrp

    for (int k0 = 0; k0 < K; k0 += BK) {
        __syncthreads();
#pragma unroll
        for (int p = 0; p < 4; ++p) {
            const size_t go = (size_t)((p & 1) * 64) * K + k0 + (p >> 1) * 32;
            lds16(ga + go, &As[p >> 1][(p & 1) * 2048 + wave * 512]);
            lds16(gb + go, &Bs[p >> 1][(p & 1) * 2048 + wave * 512]);
        }
        __syncthreads();
#pragma unroll
        for (int s = 0; s < 2; ++s) {
            short8 af[4], bfr[4];
#pragma unroll
            for (int i = 0; i < 4; ++i)
                af[i] = *(const short8*)(&As[s][(wm + i * 16 + lane15) * 32 + g_l * 8]);
#pragma unroll
            for (int j = 0; j < 4; ++j)
                bfr[j] = *(const short8*)(&Bs[s][(wn + j * 16 + lane15) * 32 + g_l * 8]);
#pragma unroll
            for (int i = 0; i < 4; ++i)
#pragma unroll
                for (int j = 0; j < 4; ++j)
                    acc[i][j] = __builtin_amdgcn_mfma_f32_16x16x32_bf16(af[i], bfr[j], acc[i][j], 0, 0, 0);
        }
    }

    const bool doRope = ROPE && (col0 < 2048);
    float invf0 = 0.f, invf1 = 0.f;
    if (ROPE) {
        invf0 = fexp2(-0.4152410118609203f * (float)lane15);
        invf1 = fexp2(-0.4152410118609203f * (float)(16 + lane15));
    }
    float bv[4];
#pragma unroll
    for (int j = 0; j < 4; ++j) bv[j] = bias[col0 + wn + j * 16 + lane15];

#pragma unroll
    for (int i = 0; i < 4; ++i) {
#pragma unroll
        for (int r = 0; r < 4; ++r) {
            int row = row0 + wm + i * 16 + lgrp * 4 + r;
            float v[4];
#pragma unroll
            for (int j = 0; j < 4; ++j) v[j] = acc[i][j][r] + bv[j];
            if (doRope) {
                float pos = (float)(row & (SS - 1));
                float s0, c0, s1, c1;
                __sincosf(pos * invf0, &s0, &c0);
                __sincosf(pos * invf1, &s1, &c1);
                float t0 = v[0] * c0 - v[2] * s0;
                float t1 = v[1] * c1 - v[3] * s1;
                float t2 = v[2] * c0 + v[0] * s0;
                float t3 = v[3] * c1 + v[1] * s1;
                v[0] = t0; v[1] = t1; v[2] = t2; v[3] = t3;
            }
#pragma unroll
            for (int j = 0; j < 4; ++j) {
                float o = v[j];
                if (ACT == 1) o = fast_gelu(o);
                Cout[(size_t)row * N + col0 + wn + j * 16 + lane15] = __float2bfloat16(o);
            }
        }
    }
}

// ---------------------------------------------------------------------------
// Split-K bf16 MFMA GEMM, BK=64, swizzled LDS, writes fp32 partials P[z][M][N]
// ---------------------------------------------------------------------------
__global__ __launch_bounds__(256) void gemm_bt_splitk(const bf16* __restrict__ A,
                                                      const bf16* __restrict__ Bt,
                                                      float* __restrict__ P,
                                                      int M, int N, int K, int KCH) {
    constexpr int BK = 64;
    __shared__ bf16 As[2][128 * 32];
    __shared__ bf16 Bs[2][128 * 32];
    const int tid = threadIdx.x;
    const int wave = tid >> 6, lane = tid & 63;
    const int lane15 = lane & 15, lgrp = lane >> 4;
    const int wm = (wave >> 1) * 64, wn = (wave & 1) * 64;
    int bx, by; xcd_remap(bx, by);
    const int row0 = by * 128, col0 = bx * 128;
    const int kbase = blockIdx.z * KCH;
    float* Cp = P + (size_t)blockIdx.z * M * N;

    floatx4 acc[4][4] = {};

    const int srow = wave * 16 + (lane >> 2);
    const int scol = (((lane & 3) + (srow >> 1)) & 3) * 8;
    const bf16* ga = A  + (size_t)(row0 + srow) * K + scol;
    const bf16* gb = Bt + (size_t)(col0 + srow) * K + scol;
    const int g_l = (lgrp - (lane15 >> 1)) & 3;

    for (int k0 = kbase; k0 < kbase + KCH; k0 += BK) {
        __syncthreads();
#pragma unroll
        for (int p = 0; p < 4; ++p) {
            const size_t go = (size_t)((p & 1) * 64) * K + k0 + (p >> 1) * 32;
            lds16(ga + go, &As[p >> 1][(p & 1) * 2048 + wave * 512]);
            lds16(gb + go, &Bs[p >> 1][(p & 1) * 2048 + wave * 512]);
        }
        __syncthreads();
#pragma unroll
        for (int s = 0; s < 2; ++s) {
            short8 af[4], bfr[4];
#pragma unroll
            for (int i = 0; i < 4; ++i)
                af[i] = *(const short8*)(&As[s][(wm + i * 16 + lane15) * 32 + g_l * 8]);
#pragma unroll
            for (int j = 0; j < 4; ++j)
                bfr[j] = *(const short8*)(&Bs[s][(wn + j * 16 + lane15) * 32 + g_l * 8]);
#pragma unroll
            for (int i = 0; i < 4; ++i)
#pragma unroll
                for (int j = 0; j < 4; ++j)
                    acc[i][j] = __builtin_amdgcn_mfma_f32_16x16x32_bf16(af[i], bfr[j], acc[i][j], 0, 0, 0);
        }
    }

#pragma unroll
    for (int i = 0; i < 4; ++i)
#pragma unroll
        for (int j = 0; j < 4; ++j) {
            int col = col0 + wn + j * 16 + lane15;
#pragma unroll
            for (int r = 0; r < 4; ++r) {
                int row = row0 + wm + i * 16 + lgrp * 4 + r;
                Cp[(size_t)row * N + col] = acc[i][j][r];
            }
        }
}

// ---------------------------------------------------------------------------
// MFMA flash attention, no-max softmax, split-KV=2, swizzled K/V LDS.
// Block = 4 waves x 32 q-rows = 128 q-rows; grid (16, Hc, BB*2) = 1024 blocks.
// ---------------------------------------------------------------------------
__global__ __launch_bounds__(256) void attn_mfma(const bf16* __restrict__ qkv,
                                                 const bf16* __restrict__ vT,
                                                 const unsigned char* __restrict__ mask,
                                                 float* __restrict__ Op,
                                                 float* __restrict__ Lp) {
    __shared__ short Klds[2][64][32];     // [kstep][key][32k]   8 KB (swizzled)
    __shared__ short Vlds[2][64][32];     // [kstep][d][32k]     8 KB (swizzled)
    __shared__ short Ps[4][32][72];       // per-wave P (Q-staging overlay) 18 KB
    __shared__ float mkf[64];

    const int h = blockIdx.y;
    const int b = blockIdx.z >> 1, kc = blockIdx.z & 1;
    const int q0 = blockIdx.x * 128;
    const int tid = threadIdx.x;
    const int wave = tid >> 6, lane = tid & 63;
    const int lane15 = lane & 15, lgrp = lane >> 4;
    const short* qs = (const short*)qkv;
    const short* vs = (const short*)vT + (size_t)(b * Hc + h) * 64 * SS;
    const int g_l = (lgrp - (lane15 >> 1)) & 3;   // swizzled read slot

    short* qstage = &Ps[wave][0][0];
#pragma unroll
    for (int i = 0; i < 4; ++i) {
        int idx = i * 64 + lane;   // unit of 8 shorts
        int g = idx & 3, row = (idx >> 2) & 15, s = (idx >> 6) & 1, mi = idx >> 7;
        const short* gq = qs + (size_t)(b * SS + q0 + wave * 32 + mi * 16 + row) * 3072
                             + h * 64 + s * 32 + g * 8;
        lds16(gq, qstage + idx * 8);
    }
    __syncthreads();
    short8 aQ[2][2];
#pragma unroll
    for (int mi = 0; mi < 2; ++mi)
#pragma unroll
        for (int s = 0; s < 2; ++s)
            aQ[mi][s] = *(const short8*)(qstage + ((mi * 2 + s) * 16 + lane15) * 32 + lgrp * 8);

    const short8 bOnes = (short8)(short)0x3F80;   // bf16 1.0 x8
    floatx4 O[2][4] = {};
    floatx4 Lacc[2] = {};
    const float cscale = 0.18033688011112042f; // 0.125 * log2(e)

    for (int t = 0; t < 16; ++t) {
        const int k0 = kc * 1024 + t * 64;
        __syncthreads();   // WAR on Klds/Vlds + Ps overlay (first iter)
#pragma unroll
        for (int i = 0; i < 2; ++i) {
            int idx = wave * 128 + i * 64 + lane;
            int g = idx & 3, row = (idx >> 2) & 63, s = idx >> 8;
            int gsw = (g + (row >> 1)) & 3;
            const short* gk = qs + (size_t)(b * SS + k0 + row) * 3072 + 1024
                                 + h * 64 + s * 32 + gsw * 8;
            lds16(gk, &Klds[0][0][0] + idx * 8);
        }
#pragma unroll
        for (int i = 0; i < 2; ++i) {
            int idx = wave * 128 + i * 64 + lane;
            int g = idx & 3, drow = (idx >> 2) & 63, s = idx >> 8;
            int gsw = (g + (drow >> 1)) & 3;
            const short* gv = vs + (size_t)drow * SS + k0 + s * 32 + gsw * 8;
            lds16(gv, &Vlds[0][0][0] + idx * 8);
        }
        if (tid < 16) {
            const unsigned char* mp = mask + b * SS + k0 + tid * 4;
#pragma unroll
            for (int j = 0; j < 4; ++j) mkf[tid * 4 + j] = mp[j] ? -1e30f : 0.0f;
        }
        __syncthreads();

        short8 bK[4][2];
#pragma unroll
        for (int j = 0; j < 4; ++j)
#pragma unroll
            for (int s = 0; s < 2; ++s)
                bK[j][s] = *(const short8*)&Klds[s][j * 16 + lane15][g_l * 8];
        floatx4 Sf[2][4] = {};
#pragma unroll
        for (int mi = 0; mi < 2; ++mi)
#pragma unroll
            for (int j = 0; j < 4; ++j)
#pragma unroll
                for (int s = 0; s < 2; ++s)
                    Sf[mi][j] = __builtin_amdgcn_mfma_f32_16x16x32_bf16(aQ[mi][s], bK[j][s], Sf[mi][j], 0, 0, 0);

        float mkv[4];
#pragma unroll
        for (int j = 0; j < 4; ++j) mkv[j] = mkf[j * 16 + lane15];

#pragma unroll
        for (int mi = 0; mi < 2; ++mi)
#pragma unroll
            for (int r = 0; r < 4; ++r)
#pragma unroll
                for (int j = 0; j < 4; ++j) {
                    float p = fexp2(Sf[mi][j][r] * cscale + mkv[j]);
                    bf16 tt = __float2bfloat16(p);
                    Ps[wave][mi * 16 + lgrp * 4 + r][lane15 + 16 * j] = *(short*)&tt;
                }

        short8 aP[2][2], bV[4][2];
#pragma unroll
        for (int mi = 0; mi < 2; ++mi)
#pragma unroll
            for (int s = 0; s < 2; ++s)
                aP[mi][s] = *(const short8*)&Ps[wave][mi * 16 + lane15][s * 32 + lgrp * 8];
#pragma unroll
        for (int jd = 0; jd < 4; ++jd)
#pragma unroll
            for (int s = 0; s < 2; ++s)
                bV[jd][s] = *(const short8*)&Vlds[s][jd * 16 + lane15][g_l * 8];
#pragma unroll
        for (int mi = 0; mi < 2; ++mi) {
#pragma unroll
            for (int jd = 0; jd < 4; ++jd)
#pragma unroll
                for (int s = 0; s < 2; ++s)
                    O[mi][jd] = __builtin_amdgcn_mfma_f32_16x16x32_bf16(aP[mi][s], bV[jd][s], O[mi][jd], 0, 0, 0);
#pragma unroll
            for (int s = 0; s < 2; ++s)
                Lacc[mi] = __builtin_amdgcn_mfma_f32_16x16x32_bf16(aP[mi][s], bOnes, Lacc[mi], 0, 0, 0);
        }
    }

    float* myOp = Op + (size_t)kc * TOK * DIMc;
#pragma unroll
    for (int mi = 0; mi < 2; ++mi)
#pragma unroll
        for (int r = 0; r < 4; ++r) {
            int q = q0 + wave * 32 + mi * 16 + lgrp * 4 + r;
            size_t rowoff = (size_t)(b * SS + q) * DIMc + h * 64 + lane15;
#pragma unroll
            for (int jd = 0; jd < 4; ++jd)
                myOp[rowoff + jd * 16] = O[mi][jd][r];
            if (lane15 == 0)
                Lp[((size_t)kc * TOK + b * SS + q) * Hc + h] = Lacc[mi][r];
        }
}

// ---------------------------------------------------------------------------
// Combine split-KV partials: ctx = (O0 + O1) / (L0 + L1), bf16 out
// ---------------------------------------------------------------------------
__global__ __launch_bounds__(256) void attn_combine(const float* __restrict__ Op,
                                                    const float* __restrict__ Lp,
                                                    bf16* __restrict__ ctx) {
    int t = blockIdx.x;
    int tid = threadIdx.x;
    int h = tid >> 4;
    size_t f = (size_t)t * (DIMc / 4) + tid;
    float4 p0 = ((const float4*)Op)[f];
    float4 p1 = ((const float4*)Op)[f + (size_t)TOK * DIMc / 4];
    float inv = 1.0f / (Lp[(size_t)t * Hc + h] + Lp[((size_t)TOK + t) * Hc + h]);
    size_t base = (size_t)t * DIMc + tid * 4;
    ctx[base + 0] = __float2bfloat16((p0.x + p1.x) * inv);
    ctx[base + 1] = __float2bfloat16((p0.y + p1.y) * inv);
    ctx[base + 2] = __float2bfloat16((p0.z + p1.z) * inv);
    ctx[base + 3] = __float2bfloat16((p0.w + p1.w) * inv);
}

// ---------------------------------------------------------------------------
extern "C" void kernel_launch(void* const* d_in, const int* in_sizes, int n_in,
                              void* d_out, int out_size, void* d_ws, size_t ws_size,
                              hipStream_t stream) {
    const float* x      = (const float*)d_in[0];
    const unsigned char* pmask = (const unsigned char*)d_in[1];
    const float* qkv_w  = (const float*)d_in[2];
    const float* qkv_b  = (const float*)d_in[3];
    const float* out_w  = (const float*)d_in[4];
    const float* out_b  = (const float*)d_in[5];
    const float* ln1_g  = (const float*)d_in[6];
    const float* ln1_b  = (const float*)d_in[7];
    const float* ln2_g  = (const float*)d_in[8];
    const float* ln2_b  = (const float*)d_in[9];
    const float* w1     = (const float*)d_in[10];
    const float* b1     = (const float*)d_in[11];
    const float* w2     = (const float*)d_in[12];
    const float* b2     = (const float*)d_in[13];
    float* out = (float*)d_out;

    char* ws = (char*)d_ws;
    bf16* wqkv_t = (bf16*)ws;                      ws += (size_t)3072 * 1024 * 2;
    bf16* wout_t = (bf16*)ws;                      ws += (size_t)1024 * 1024 * 2;
    bf16* w1_t   = (bf16*)ws;                      ws += (size_t)4096 * 1024 * 2;
    bf16* w2_t   = (bf16*)ws;                      ws += (size_t)1024 * 4096 * 2;
    bf16* h_bf   = (bf16*)ws;                      ws += (size_t)TOK * DIMc * 2;
    bf16* qkv_bf = (bf16*)ws;                      ws += (size_t)TOK * 3 * DIMc * 2;
    bf16* ctx_bf = (bf16*)ws;                      ws += (size_t)TOK * DIMc * 2;
    float* partial = (float*)ws;                   ws += (size_t)2 * TOK * DIMc * 4; // 32 MB
    float* Lp      = (float*)ws;                   ws += (size_t)2 * TOK * Hc * 4;   // 0.5 MB
    bf16* ffn1_bf = qkv_bf;          // overlay over dead qkv+ctx
    bf16* vT      = h_bf;            // overlay: h_bf dead between QKV gemm and reduce_ln

    transpose_bf16<<<dim3(3072 / 32, 1024 / 32), 256, 0, stream>>>(qkv_w, wqkv_t, 1024, 3072);
    transpose_bf16<<<dim3(1024 / 32, 1024 / 32), 256, 0, stream>>>(out_w, wout_t, 1024, 1024);
    transpose_bf16<<<dim3(4096 / 32, 1024 / 32), 256, 0, stream>>>(w1,    w1_t,   1024, 4096);
    transpose_bf16<<<dim3(1024 / 32, 4096 / 32), 256, 0, stream>>>(w2,    w2_t,   4096, 1024);

    ln_kernel<<<TOK, 256, 0, stream>>>(x, ln1_g, ln1_b, h_bf);
    // QKV + fused RoPE on q/k tiles
    gemm_bt<0, true><<<dim3(3072 / 128, TOK / 128), 256, 0, stream>>>(
        h_bf, wqkv_t, qkv_b, qkv_bf, TOK, 3 * DIMc, DIMc);
    // V pre-transpose (into dead h_bf region)
    transpose_v<<<dim3(SS / 64, Hc, BB), 256, 0, stream>>>(qkv_bf, vT);
    // attention: split-KV=2, partials + combine
    attn_mfma<<<dim3(SS / 128, Hc, BB * 2), 256, 0, stream>>>(qkv_bf, vT, pmask, partial, Lp);
    attn_combine<<<TOK, 256, 0, stream>>>(partial, Lp, ctx_bf);

    // out projection: split-K=2 -> fp32 partials, then fused reduce+residual+LN2
    gemm_bt_splitk<<<dim3(1024 / 128, TOK / 128, 2), 256, 0, stream>>>(
        ctx_bf, wout_t, partial, TOK, DIMc, DIMc, 512);
    reduce_ln_kernel<<<TOK, 256, 0, stream>>>(partial, x, out_b, ln2_g, ln2_b, out, h_bf);

    // FFN1 + fast GELU
    gemm_bt<1, false><<<dim3(4096 / 128, TOK / 128), 256, 0, stream>>>(
        h_bf, w1_t, b1, ffn1_bf, TOK, FFNc, DIMc);
    // FFN2: split-K=2 -> partials, then elementwise reduce+bias into out
    gemm_bt_splitk<<<dim3(1024 / 128, TOK / 128, 2), 256, 0, stream>>>(
        ffn1_bf, w2_t, partial, TOK, DIMc, FFNc, 2048);
    reduce_add_kernel<<<TOK * DIMc / 4 / 256, 256, 0, stream>>>(partial, b2, out);
}